// Round 1
// baseline (3041.121 us; speedup 1.0000x reference)
//
#include <hip/hip_runtime.h>
#include <hip/hip_bf16.h>

#define BB 16
#define NN 500
#define DD 128
#define QK 256          // 2 branches * 8 heads * 16 kd
#define NORMC 0.25f     // 1/sqrt(16)
#define TIJ 32
#define LDSP 264        // bf16 row stride: 528B = 33*16B (aligned), 132 dwords -> 4*row bank offset

typedef unsigned short u16;
typedef unsigned int u32;

__device__ inline float bf2f(u16 s) {
  union { u32 u; float f; } uf; uf.u = ((u32)s) << 16; return uf.f;
}

// K1: per-b max over N, then graph projections -> gp[b][128], gh[b][128]
__global__ __launch_bounds__(128) void k_graph(
    const float* __restrict__ h_em, const float* __restrict__ pos_em,
    const float* __restrict__ Pgp, const float* __restrict__ Pgn,
    float* __restrict__ gp, float* __restrict__ gh) {
  int b = blockIdx.x, d = threadIdx.x;
  __shared__ float mp[DD], mh[DD];
  const float* ph = h_em + (size_t)b * NN * DD + d;
  const float* pp = pos_em + (size_t)b * NN * DD + d;
  float vh = -1e30f, vp = -1e30f;
  for (int n = 0; n < NN; ++n) {
    vh = fmaxf(vh, ph[(size_t)n * DD]);
    vp = fmaxf(vp, pp[(size_t)n * DD]);
  }
  mp[d] = vp; mh[d] = vh;
  __syncthreads();
  float ap = 0.f, ah = 0.f;
  #pragma unroll 8
  for (int k = 0; k < DD; ++k) {
    ap = fmaf(mp[k], Pgp[k * DD + d], ap);
    ah = fmaf(mh[k], Pgn[k * DD + d], ah);
  }
  gp[b * DD + d] = ap;
  gh[b * DD + d] = ah;
}

// K2: per (b,n): refined h (node proj + graph bias), then Q/K for both branches.
// Qc/Kc layout: [b][n][c], c in 0..255; c<128 = pos branch (h=c/16,k=c%16), c>=128 node.
// NORM folded into Qc.
__global__ __launch_bounds__(256) void k_qk(
    const float* __restrict__ h_em, const float* __restrict__ pos_em,
    const float* __restrict__ Pnp, const float* __restrict__ Pnn,
    const float* __restrict__ gp, const float* __restrict__ gh,
    const float* __restrict__ Wq_pos, const float* __restrict__ Wk_pos,
    const float* __restrict__ Wq_node, const float* __restrict__ Wk_node,
    u16* __restrict__ Qc, u16* __restrict__ Kc) {
  int bn = blockIdx.x;
  int b = bn / NN;
  int t = threadIdx.x;
  __shared__ float xs[2][DD];  // 0=pos input, 1=node input
  __shared__ float hs[2][DD];  // refined embeddings
  if (t < DD) xs[0][t] = pos_em[(size_t)bn * DD + t];
  else        xs[1][t - DD] = h_em[(size_t)bn * DD + (t - DD)];
  __syncthreads();
  {
    int br = t >> 7;          // 0 pos, 1 node
    int o = t & 127;
    const float* P = br ? Pnn : Pnp;
    const float* g = br ? gh : gp;
    const float* x = xs[br];
    float a = g[b * DD + o];
    #pragma unroll 8
    for (int k = 0; k < DD; ++k) a = fmaf(x[k], P[k * DD + o], a);
    hs[br][o] = a;
  }
  __syncthreads();
  {
    int br = t >> 7;
    int cc = t & 127;
    const float* Wq = br ? Wq_node : Wq_pos;
    const float* Wk = br ? Wk_node : Wk_pos;
    const float* x = hs[br];
    int wbase = (cc >> 4) * (DD * 16) + (cc & 15);   // h*D*KD + k
    float q = 0.f, kv = 0.f;
    #pragma unroll 8
    for (int k = 0; k < DD; ++k) {
      float xv = x[k];
      q  = fmaf(xv, Wq[wbase + k * 16], q);
      kv = fmaf(xv, Wk[wbase + k * 16], kv);
    }
    size_t off = (size_t)bn * QK + t;
    __hip_bfloat16 qb = __float2bfloat16(q * NORMC);
    __hip_bfloat16 kb = __float2bfloat16(kv);
    Qc[off] = *(u16*)&qb;
    Kc[off] = *(u16*)&kb;
  }
}

// K3: fused compat + MLP. 32x32 pair tile per block, 256 threads,
// thread t: ii = t>>3 (one i row), j in {jg, jg+8, jg+16, jg+24}, jg = t&7.
__global__ __launch_bounds__(256) void k_main(
    const u16* __restrict__ Qc, const u16* __restrict__ Kc,
    const float* __restrict__ W1, const float* __restrict__ b1,
    const float* __restrict__ W2, const float* __restrict__ b2,
    const float* __restrict__ W3, const float* __restrict__ b3,
    float* __restrict__ out) {
  int b = blockIdx.z;
  int i0 = blockIdx.y * TIJ;
  int j0 = blockIdx.x * TIJ;
  __shared__ u16 Qt[TIJ][LDSP];
  __shared__ u16 Kt[TIJ][LDSP];
  int t = threadIdx.x;
  // stage: 32 rows x 256 bf16 per array; 1024 16B-chunks per array / 256 thr = 4 reps
  #pragma unroll
  for (int rep = 0; rep < 4; ++rep) {
    int c = t + rep * 256;
    int r = c >> 5, col = c & 31;
    int gi = i0 + r; if (gi > NN - 1) gi = NN - 1;
    int gj = j0 + r; if (gj > NN - 1) gj = NN - 1;
    uint4 qv = *(const uint4*)(Qc + (size_t)(b * NN + gi) * QK + col * 8);
    uint4 kv = *(const uint4*)(Kc + (size_t)(b * NN + gj) * QK + col * 8);
    *(uint4*)(&Qt[r][col * 8]) = qv;
    *(uint4*)(&Kt[r][col * 8]) = kv;
  }
  __syncthreads();
  int ii = t >> 3, jg = t & 7;
  int gi = i0 + ii;
  float b3v = b3[0];
  #pragma unroll 1   // keep body rolled: fits I-cache, arrays stay compile-time indexed
  for (int jj = 0; jj < 4; ++jj) {
    int jr = jg + 8 * jj;
    int gj = j0 + jr;
    float comp[16];
    #pragma unroll
    for (int h = 0; h < 16; ++h) {
      float acc = 0.f;
      #pragma unroll
      for (int hf = 0; hf < 2; ++hf) {
        uint4 qv = *(const uint4*)(&Qt[ii][h * 16 + hf * 8]);
        uint4 kv = *(const uint4*)(&Kt[jr][h * 16 + hf * 8]);
        const u16* qs = (const u16*)&qv;
        const u16* ks = (const u16*)&kv;
        #pragma unroll
        for (int e = 0; e < 8; ++e)
          acc = fmaf(bf2f(qs[e]), bf2f(ks[e]), acc);
      }
      comp[h] = acc;
    }
    // MLP 16 -> 32 -> 32 -> 1, relu folded into next-layer reads
    float h1[32];
    #pragma unroll
    for (int o = 0; o < 32; ++o) h1[o] = b1[o];
    #pragma unroll
    for (int i = 0; i < 16; ++i) {
      float ci = comp[i];
      #pragma unroll
      for (int o = 0; o < 32; ++o) h1[o] = fmaf(ci, W1[i * 32 + o], h1[o]);
    }
    float h2[32];
    #pragma unroll
    for (int o = 0; o < 32; ++o) h2[o] = b2[o];
    #pragma unroll
    for (int i = 0; i < 32; ++i) {
      float ci = fmaxf(h1[i], 0.f);
      #pragma unroll
      for (int o = 0; o < 32; ++o) h2[o] = fmaf(ci, W2[i * 32 + o], h2[o]);
    }
    float o3 = b3v;
    #pragma unroll
    for (int i = 0; i < 32; ++i) o3 = fmaf(fmaxf(h2[i], 0.f), W3[i], o3);
    if (gi < NN && gj < NN) out[((size_t)b * NN + gi) * NN + gj] = o3;
  }
}

extern "C" void kernel_launch(void* const* d_in, const int* in_sizes, int n_in,
                              void* d_out, int out_size, void* d_ws, size_t ws_size,
                              hipStream_t stream) {
  const float* h_em    = (const float*)d_in[0];
  const float* pos_em  = (const float*)d_in[1];
  // d_in[2] solving_state_for_net: unused by the reference output
  const float* Wq_pos  = (const float*)d_in[3];
  const float* Wk_pos  = (const float*)d_in[4];
  const float* Wq_node = (const float*)d_in[5];
  const float* Wk_node = (const float*)d_in[6];
  const float* Pgp     = (const float*)d_in[7];
  const float* Pgn     = (const float*)d_in[8];
  const float* Pnp     = (const float*)d_in[9];
  const float* Pnn     = (const float*)d_in[10];
  const float* W1 = (const float*)d_in[11];
  const float* b1 = (const float*)d_in[12];
  const float* W2 = (const float*)d_in[13];
  const float* b2 = (const float*)d_in[14];
  const float* W3 = (const float*)d_in[15];
  const float* b3 = (const float*)d_in[16];
  float* outp = (float*)d_out;

  // ws layout: gp [B][128] f32 @0, gh @8192, Qc bf16 @16384, Kc bf16 after
  float* gp = (float*)d_ws;
  float* gh = gp + BB * DD;
  u16* Qc = (u16*)((char*)d_ws + 16384);
  u16* Kc = Qc + (size_t)BB * NN * QK;

  hipLaunchKernelGGL(k_graph, dim3(BB), dim3(DD), 0, stream,
                     h_em, pos_em, Pgp, Pgn, gp, gh);
  hipLaunchKernelGGL(k_qk, dim3(BB * NN), dim3(256), 0, stream,
                     h_em, pos_em, Pnp, Pnn, gp, gh,
                     Wq_pos, Wk_pos, Wq_node, Wk_node, Qc, Kc);
  hipLaunchKernelGGL(k_main, dim3(16, 16, BB), dim3(256), 0, stream,
                     Qc, Kc, W1, b1, W2, b2, W3, b3, outp);
}

// Round 2
// 285.075 us; speedup vs baseline: 10.6678x; 10.6678x over previous
//
#include <hip/hip_runtime.h>
#include <hip/hip_bf16.h>

#define BB 16
#define NN 500
#define DD 128
#define QKC 256         // 2 branches * 8 heads * 16 kd
#define NORMC 0.25f     // 1/sqrt(16), exact power of 2

typedef unsigned short u16;
typedef unsigned int u32;
typedef __attribute__((ext_vector_type(8))) short bf16x8;   // 4 VGPRs, MFMA A/B frag
typedef __attribute__((ext_vector_type(16))) float f32x16;  // MFMA C/D frag

__device__ inline u16 f2bf(float f) {
  __hip_bfloat16 h = __float2bfloat16(f);
  return *(u16*)&h;
}
__device__ inline float bf2f(u16 s) {
  union { u32 u; float f; } uf; uf.u = ((u32)s) << 16; return uf.f;
}

// K1: per-b max over N (8-way split over N), then graph projections -> gp/gh [B][128]
__global__ __launch_bounds__(1024) void k_graph(
    const float* __restrict__ h_em, const float* __restrict__ pos_em,
    const float* __restrict__ Pgp, const float* __restrict__ Pgn,
    float* __restrict__ gp, float* __restrict__ gh) {
  int b = blockIdx.x, t = threadIdx.x;
  int d = t & 127, st = t >> 7;
  __shared__ float smp[8][128], smh[8][128], mp[128], mh[128];
  float vp = -1e30f, vh = -1e30f;
  const float* ph = h_em + (size_t)b * NN * DD + d;
  const float* pp = pos_em + (size_t)b * NN * DD + d;
  for (int n = st; n < NN; n += 8) {
    vh = fmaxf(vh, ph[(size_t)n * DD]);
    vp = fmaxf(vp, pp[(size_t)n * DD]);
  }
  smp[st][d] = vp; smh[st][d] = vh;
  __syncthreads();
  if (t < 128) {
    float ap = smp[0][t], ah = smh[0][t];
    #pragma unroll
    for (int s = 1; s < 8; ++s) { ap = fmaxf(ap, smp[s][t]); ah = fmaxf(ah, smh[s][t]); }
    mp[t] = ap; mh[t] = ah;
  }
  __syncthreads();
  if (t < 256) {
    int br = t >> 7, o = t & 127;
    const float* P = br ? Pgn : Pgp;
    const float* m = br ? mh : mp;
    float a = 0.f;
    #pragma unroll 8
    for (int k = 0; k < DD; ++k) a = fmaf(m[k], P[k * DD + o], a);
    (br ? gh : gp)[b * DD + o] = a;
  }
}

// K2: per (b,n): refined embedding then Q/K (bf16, NORM folded into Q).
// Qc/Kc layout [b][n][c], c=ch*16+k, ch 0..7 pos heads, 8..15 node heads.
__global__ __launch_bounds__(256) void k_qk(
    const float* __restrict__ h_em, const float* __restrict__ pos_em,
    const float* __restrict__ Pnp, const float* __restrict__ Pnn,
    const float* __restrict__ gp, const float* __restrict__ gh,
    const float* __restrict__ Wq_pos, const float* __restrict__ Wk_pos,
    const float* __restrict__ Wq_node, const float* __restrict__ Wk_node,
    u16* __restrict__ Qc, u16* __restrict__ Kc) {
  int bn = blockIdx.x;
  int b = bn / NN;
  int t = threadIdx.x;
  __shared__ float xs[2][DD];
  __shared__ float hs[2][DD];
  if (t < DD) xs[0][t] = pos_em[(size_t)bn * DD + t];
  else        xs[1][t - DD] = h_em[(size_t)bn * DD + (t - DD)];
  __syncthreads();
  {
    int br = t >> 7, o = t & 127;
    const float* P = br ? Pnn : Pnp;
    const float* g = br ? gh : gp;
    const float* x = xs[br];
    float a = g[b * DD + o];
    #pragma unroll 8
    for (int k = 0; k < DD; ++k) a = fmaf(x[k], P[k * DD + o], a);
    hs[br][o] = a;
  }
  __syncthreads();
  {
    int br = t >> 7, cc = t & 127;
    const float* Wq = br ? Wq_node : Wq_pos;
    const float* Wk = br ? Wk_node : Wk_pos;
    const float* x = hs[br];
    int wbase = (cc >> 4) * (DD * 16) + (cc & 15);
    float qv = 0.f, kv = 0.f;
    #pragma unroll 8
    for (int k = 0; k < DD; ++k) {
      float xv = x[k];
      qv = fmaf(xv, Wq[wbase + k * 16], qv);
      kv = fmaf(xv, Wk[wbase + k * 16], kv);
    }
    size_t off = (size_t)bn * QKC + t;
    Qc[off] = f2bf(qv * NORMC);
    Kc[off] = f2bf(kv);
  }
}

// K3: MFMA-based compat + MLP. One 32x32 pair tile per 256-thread block (4 waves).
// LDS map (80 KB):
//   [0..16K)    Qt: 32 rows x 256 bf16 (512B rows), 16B-slot XOR-swizzle by (row&7)
//   [16K..32K)  Kt: same
//   (reused after compat barrier)
//   [0..10240)       H1: per-wave [32 j][40 u16] (80B rows, bf16, 8 pad)
//   [10240..27136)   H2: per-wave [32 j][33 f32] (conflict-free (j+o)%32 banks)
//   [32K..80K)  CM: compat bf16 [32 i][32 j][24 u16] (16 ch + 8 pad -> 48B j-stride)
__global__ __launch_bounds__(256) void k_main(
    const u16* __restrict__ Qc, const u16* __restrict__ Kc,
    const float* __restrict__ W1, const float* __restrict__ b1,
    const float* __restrict__ W2, const float* __restrict__ b2,
    const float* __restrict__ W3, const float* __restrict__ b3,
    float* __restrict__ out) {
  __shared__ __align__(16) char sm[81920];
  int t = threadIdx.x;
  int l = t & 63, w = t >> 6;
  int o = l & 31, q = l >> 5;
  int b = blockIdx.z, i0 = blockIdx.y * 32, j0 = blockIdx.x * 32;

  // ---- weight fragments (B-operand layout: col=lane&31, k=8*(lane>>5)+e)
  bf16x8 w1f, w2f0, w2f1;
  #pragma unroll
  for (int e = 0; e < 8; ++e) {
    w1f[e]  = (short)f2bf(W1[(8 * q + e) * 32 + o]);
    w2f0[e] = (short)f2bf(W2[(8 * q + e) * 32 + o]);
    w2f1[e] = (short)f2bf(W2[(16 + 8 * q + e) * 32 + o]);
  }
  float b1v = b1[o], b2v = b2[o], b3v = b3[0];
  float vw3[16];
  #pragma unroll
  for (int e = 0; e < 16; ++e) vw3[e] = W3[16 * q + e];

  // ---- stage Q/K tiles (rows clamped; stores masked later)
  u16* Qt = (u16*)sm;
  u16* Kt = (u16*)(sm + 16384);
  #pragma unroll
  for (int rep = 0; rep < 4; ++rep) {
    int s = t + rep * 256;           // 1024 16B-slots per array
    int r = s >> 5, c = s & 31;
    int gi = i0 + r; if (gi >= NN) gi = NN - 1;
    int gj = j0 + r; if (gj >= NN) gj = NN - 1;
    uint4 qv = *(const uint4*)(Qc + ((size_t)b * NN + gi) * QKC + c * 8);
    uint4 kv = *(const uint4*)(Kc + ((size_t)b * NN + gj) * QKC + c * 8);
    int cs = c ^ (r & 7);
    *(uint4*)(Qt + r * 256 + cs * 8) = qv;
    *(uint4*)(Kt + r * 256 + cs * 8) = kv;
  }
  __syncthreads();

  // ---- compat: wave w computes channels 4w..4w+3 via mfma 32x32x16 (K=16 exact)
  u16* CM = (u16*)(sm + 32768);      // u16 index: i*768 + j*24 + ch
  {
    f32x16 cz;
    #pragma unroll
    for (int r = 0; r < 16; ++r) cz[r] = 0.f;
    f32x16 cc[4];
    #pragma unroll
    for (int m = 0; m < 4; ++m) {
      int ch = 4 * w + m;
      int slot = (ch * 2 + q) ^ (o & 7);   // A row i = o; B col j = o
      bf16x8 a  = *(const bf16x8*)(Qt + o * 256 + slot * 8);
      bf16x8 bb = *(const bf16x8*)(Kt + o * 256 + slot * 8);
      cc[m] = __builtin_amdgcn_mfma_f32_32x32x16_bf16(a, bb, cz, 0, 0, 0);
    }
    // C layout: col(j)=lane&31, row(i)=(r&3)+8*(r>>2)+4*(lane>>5)
    #pragma unroll
    for (int r = 0; r < 16; ++r) {
      int i = (r & 3) + 8 * (r >> 2) + 4 * q;
      u32 d0 = (u32)f2bf(cc[0][r]) | ((u32)f2bf(cc[1][r]) << 16);
      u32 d1 = (u32)f2bf(cc[2][r]) | ((u32)f2bf(cc[3][r]) << 16);
      uint2 dd = make_uint2(d0, d1);
      *(uint2*)(CM + i * 768 + o * 24 + 4 * w) = dd;
    }
  }
  __syncthreads();

  // ---- MLP: wave w owns i-steps 8w..8w+7 (32 pairs each)
  u16*  H1 = (u16*)(sm + w * 2560);
  float* H2 = (float*)(sm + 10240 + w * 4224);
  #pragma unroll 1
  for (int s = 0; s < 8; ++s) {
    int i = 8 * w + s;
    int gi = i0 + i;
    // layer1: [32 j x 16ch] @ W1 -> [32 j x 32 o], bias via C-init
    bf16x8 a1 = *(const bf16x8*)(CM + i * 768 + o * 24 + 8 * q);
    f32x16 c1;
    #pragma unroll
    for (int r = 0; r < 16; ++r) c1[r] = b1v;
    c1 = __builtin_amdgcn_mfma_f32_32x32x16_bf16(a1, w1f, c1, 0, 0, 0);
    #pragma unroll
    for (int r = 0; r < 16; ++r) {
      int j = (r & 3) + 8 * (r >> 2) + 4 * q;
      H1[j * 40 + o] = f2bf(fmaxf(c1[r], 0.f));
    }
    // layer2: K=32 as two K=16 mfmas
    bf16x8 a2a = *(const bf16x8*)(H1 + o * 40 + 8 * q);
    bf16x8 a2b = *(const bf16x8*)(H1 + o * 40 + 16 + 8 * q);
    f32x16 c2;
    #pragma unroll
    for (int r = 0; r < 16; ++r) c2[r] = b2v;
    c2 = __builtin_amdgcn_mfma_f32_32x32x16_bf16(a2a, w2f0, c2, 0, 0, 0);
    c2 = __builtin_amdgcn_mfma_f32_32x32x16_bf16(a2b, w2f1, c2, 0, 0, 0);
    #pragma unroll
    for (int r = 0; r < 16; ++r) {
      int j = (r & 3) + 8 * (r >> 2) + 4 * q;
      H2[j * 33 + o] = fmaxf(c2[r], 0.f);
    }
    // layer3: each half sums 16 of 32 channels for pair j=o, then cross-half add
    float acc = 0.f;
    #pragma unroll
    for (int e = 0; e < 16; ++e)
      acc = fmaf(H2[o * 33 + 16 * q + e], vw3[e], acc);
    acc += __shfl_xor(acc, 32);
    if (l < 32 && gi < NN && j0 + o < NN)
      out[((size_t)b * NN + gi) * NN + j0 + o] = acc + b3v;
  }
}

extern "C" void kernel_launch(void* const* d_in, const int* in_sizes, int n_in,
                              void* d_out, int out_size, void* d_ws, size_t ws_size,
                              hipStream_t stream) {
  const float* h_em    = (const float*)d_in[0];
  const float* pos_em  = (const float*)d_in[1];
  const float* Wq_pos  = (const float*)d_in[3];
  const float* Wk_pos  = (const float*)d_in[4];
  const float* Wq_node = (const float*)d_in[5];
  const float* Wk_node = (const float*)d_in[6];
  const float* Pgp     = (const float*)d_in[7];
  const float* Pgn     = (const float*)d_in[8];
  const float* Pnp     = (const float*)d_in[9];
  const float* Pnn     = (const float*)d_in[10];
  const float* W1 = (const float*)d_in[11];
  const float* b1 = (const float*)d_in[12];
  const float* W2 = (const float*)d_in[13];
  const float* b2 = (const float*)d_in[14];
  const float* W3 = (const float*)d_in[15];
  const float* b3 = (const float*)d_in[16];
  float* outp = (float*)d_out;

  float* gp = (float*)d_ws;
  float* gh = gp + BB * DD;
  u16* Qc = (u16*)((char*)d_ws + 16384);
  u16* Kc = Qc + (size_t)BB * NN * QKC;

  hipLaunchKernelGGL(k_graph, dim3(BB), dim3(1024), 0, stream,
                     h_em, pos_em, Pgp, Pgn, gp, gh);
  hipLaunchKernelGGL(k_qk, dim3(BB * NN), dim3(256), 0, stream,
                     h_em, pos_em, Pnp, Pnn, gp, gh,
                     Wq_pos, Wk_pos, Wq_node, Wk_node, Qc, Kc);
  hipLaunchKernelGGL(k_main, dim3(16, 16, BB), dim3(256), 0, stream,
                     Qc, Kc, W1, b1, W2, b2, W3, b3, outp);
}

// Round 5
// 277.056 us; speedup vs baseline: 10.9765x; 1.0289x over previous
//
#include <hip/hip_runtime.h>
#include <hip/hip_bf16.h>

#define BB 16
#define NN 500
#define DD 128
#define QKC 256         // 2 branches * 8 heads * 16 kd
#define NORMC 0.25f     // 1/sqrt(16)

typedef unsigned short u16;
typedef unsigned int u32;
typedef __attribute__((ext_vector_type(8))) short bf16x8;   // MFMA A/B frag
typedef __attribute__((ext_vector_type(16))) float f32x16;  // MFMA C/D frag

__device__ inline u16 f2bf(float f) {
  __hip_bfloat16 h = __float2bfloat16(f);
  return *(u16*)&h;
}
__device__ inline float bf2f(u16 s) {
  union { u32 u; float f; } uf; uf.u = ((u32)s) << 16; return uf.f;
}

// ===== K1 (known good): per-b max over N, graph projections =====
__global__ __launch_bounds__(1024) void k_graph(
    const float* __restrict__ h_em, const float* __restrict__ pos_em,
    const float* __restrict__ Pgp, const float* __restrict__ Pgn,
    float* __restrict__ gp, float* __restrict__ gh) {
  int b = blockIdx.x, t = threadIdx.x;
  int d = t & 127, st = t >> 7;
  __shared__ float smp[8][128], smh[8][128], mp[128], mh[128];
  float vp = -1e30f, vh = -1e30f;
  const float* ph = h_em + (size_t)b * NN * DD + d;
  const float* pp = pos_em + (size_t)b * NN * DD + d;
  for (int n = st; n < NN; n += 8) {
    vh = fmaxf(vh, ph[(size_t)n * DD]);
    vp = fmaxf(vp, pp[(size_t)n * DD]);
  }
  smp[st][d] = vp; smh[st][d] = vh;
  __syncthreads();
  if (t < 128) {
    float ap = smp[0][t], ah = smh[0][t];
    #pragma unroll
    for (int s = 1; s < 8; ++s) { ap = fmaxf(ap, smp[s][t]); ah = fmaxf(ah, smh[s][t]); }
    mp[t] = ap; mh[t] = ah;
  }
  __syncthreads();
  if (t < 256) {
    int br = t >> 7, o = t & 127;
    const float* P = br ? Pgn : Pgp;
    const float* m = br ? mh : mp;
    float a = 0.f;
    #pragma unroll 8
    for (int k = 0; k < DD; ++k) a = fmaf(m[k], P[k * DD + o], a);
    (br ? gh : gp)[b * DD + o] = a;
  }
}

// ===== K2 (known good): per (b,n) refined embedding then Q/K =====
__global__ __launch_bounds__(256) void k_qk(
    const float* __restrict__ h_em, const float* __restrict__ pos_em,
    const float* __restrict__ Pnp, const float* __restrict__ Pnn,
    const float* __restrict__ gp, const float* __restrict__ gh,
    const float* __restrict__ Wq_pos, const float* __restrict__ Wk_pos,
    const float* __restrict__ Wq_node, const float* __restrict__ Wk_node,
    u16* __restrict__ Qc, u16* __restrict__ Kc) {
  int bn = blockIdx.x;
  int b = bn / NN;
  int t = threadIdx.x;
  __shared__ float xs[2][DD];
  __shared__ float hs[2][DD];
  if (t < DD) xs[0][t] = pos_em[(size_t)bn * DD + t];
  else        xs[1][t - DD] = h_em[(size_t)bn * DD + (t - DD)];
  __syncthreads();
  {
    int br = t >> 7, o = t & 127;
    const float* P = br ? Pnn : Pnp;
    const float* g = br ? gh : gp;
    const float* x = xs[br];
    float a = g[b * DD + o];
    #pragma unroll 8
    for (int k = 0; k < DD; ++k) a = fmaf(x[k], P[k * DD + o], a);
    hs[br][o] = a;
  }
  __syncthreads();
  {
    int br = t >> 7, cc = t & 127;
    const float* Wq = br ? Wq_node : Wq_pos;
    const float* Wk = br ? Wk_node : Wk_pos;
    const float* x = hs[br];
    int wbase = (cc >> 4) * (DD * 16) + (cc & 15);
    float qv = 0.f, kv = 0.f;
    #pragma unroll 8
    for (int k = 0; k < DD; ++k) {
      float xv = x[k];
      qv = fmaf(xv, Wq[wbase + k * 16], qv);
      kv = fmaf(xv, Wk[wbase + k * 16], kv);
    }
    size_t off = (size_t)bn * QKC + t;
    Qc[off] = f2bf(qv * NORMC);
    Kc[off] = f2bf(kv);
  }
}

// ===== K3: MFMA compat + register MLP (transpose via shfl_xor, deterministic) =====
__global__ __launch_bounds__(256) void k_main(
    const u16* __restrict__ Qc, const u16* __restrict__ Kc,
    const float* __restrict__ W1, const float* __restrict__ b1,
    const float* __restrict__ W2, const float* __restrict__ b2,
    const float* __restrict__ W3, const float* __restrict__ b3,
    float* __restrict__ out) {
  __shared__ __align__(16) char sm[81920];
  u16* Qt = (u16*)sm;             // [32][256] swizzled slot ^ row
  u16* Kt = (u16*)(sm + 16384);
  u16* CM = (u16*)(sm + 32768);   // [32 i][32 j][24] (16 ch + 8 pad)
  int t = threadIdx.x, l = t & 63, w = t >> 6, o = l & 31, q = l >> 5;
  int b = blockIdx.z, i0 = blockIdx.y * 32, j0 = blockIdx.x * 32;

  // weight frags (A-operand = W^T: row=out-ch, k=in-ch; row=lane&31, k=8q+e)
  bf16x8 w1f, w2f0, w2f1;
  #pragma unroll
  for (int e = 0; e < 8; ++e) {
    w1f[e]  = (short)f2bf(W1[(8 * q + e) * 32 + o]);
    w2f0[e] = (short)f2bf(W2[(8 * q + e) * 32 + o]);
    w2f1[e] = (short)f2bf(W2[(16 + 8 * q + e) * 32 + o]);
  }
  f32x16 b1f, b2f;
  float vw3s[16];
  #pragma unroll
  for (int r = 0; r < 16; ++r) {
    int ch = (r & 3) + 8 * (r >> 2) + 4 * q;
    b1f[r] = b1[ch]; b2f[r] = b2[ch]; vw3s[r] = W3[ch];
  }
  float b3v = b3[0];

  // stage Q/K tiles
  #pragma unroll
  for (int rep = 0; rep < 4; ++rep) {
    int s = t + rep * 256;
    int r = s >> 5, c = s & 31;
    int gi = i0 + r; if (gi >= NN) gi = NN - 1;
    int gj = j0 + r; if (gj >= NN) gj = NN - 1;
    uint4 qv = *(const uint4*)(Qc + ((size_t)b * NN + gi) * QKC + c * 8);
    uint4 kv = *(const uint4*)(Kc + ((size_t)b * NN + gj) * QKC + c * 8);
    int cs = c ^ r;
    *(uint4*)(Qt + r * 256 + cs * 8) = qv;
    *(uint4*)(Kt + r * 256 + cs * 8) = kv;
  }
  __syncthreads();

  // compat: wave w -> channels 4w..4w+3
  {
    f32x16 cz;
    #pragma unroll
    for (int r = 0; r < 16; ++r) cz[r] = 0.f;
    f32x16 cc[4];
    #pragma unroll
    for (int m = 0; m < 4; ++m) {
      int ch = 4 * w + m;
      int slot = (2 * ch + q) ^ o;
      bf16x8 a  = *(const bf16x8*)(Qt + o * 256 + slot * 8);
      bf16x8 bb = *(const bf16x8*)(Kt + o * 256 + slot * 8);
      cc[m] = __builtin_amdgcn_mfma_f32_32x32x16_bf16(a, bb, cz, 0, 0, 0);
    }
    #pragma unroll
    for (int r = 0; r < 16; ++r) {
      int i = (r & 3) + 8 * (r >> 2) + 4 * q;
      u32 d0 = (u32)f2bf(cc[0][r]) | ((u32)f2bf(cc[1][r]) << 16);
      u32 d1 = (u32)f2bf(cc[2][r]) | ((u32)f2bf(cc[3][r]) << 16);
      *(uint2*)(CM + i * 768 + o * 24 + 4 * w) = make_uint2(d0, d1);
    }
  }
  __syncthreads();

  // MLP: wave w owns i = 8w..8w+7; fully in registers
  #pragma unroll 1
  for (int s = 0; s < 8; ++s) {
    int i = 8 * w + s;
    int gi = i0 + i;
    // layer1 (swapped): C1[ch1][j] = W1^T @ compat^T
    bf16x8 a1 = *(const bf16x8*)(CM + i * 768 + o * 24 + 8 * q);
    f32x16 c1 = __builtin_amdgcn_mfma_f32_32x32x16_bf16(w1f, a1, b1f, 0, 0, 0);
    // relu -> bf16 pack: Pw[p] = rows (base+4q, base+4q+1) per mapping
    u32 Pw[8];
    #pragma unroll
    for (int g = 0; g < 4; ++g) {
      #pragma unroll
      for (int ww = 0; ww < 2; ++ww) {
        float x0 = fmaxf(c1[4 * g + 2 * ww], 0.f);
        float x1 = fmaxf(c1[4 * g + 2 * ww + 1], 0.f);
        Pw[g * 2 + ww] = (u32)f2bf(x0) | ((u32)f2bf(x1) << 16);
      }
    }
    // cross-half redistribute via shfl_xor(32) + select (deterministic).
    // Lane (o,q) holds rows {4q..4q+3, 8+4q.., 16+4q.., 24+4q..} packed in Pw[0..7].
    // B-frag ba needs word w = rows (8q+2w, 8q+2w+1); bb: +16.
    u32 xp0 = (u32)__shfl_xor((int)Pw[0], 32);
    u32 xp1 = (u32)__shfl_xor((int)Pw[1], 32);
    u32 xp2 = (u32)__shfl_xor((int)Pw[2], 32);
    u32 xp3 = (u32)__shfl_xor((int)Pw[3], 32);
    u32 xp4 = (u32)__shfl_xor((int)Pw[4], 32);
    u32 xp5 = (u32)__shfl_xor((int)Pw[5], 32);
    u32 xp6 = (u32)__shfl_xor((int)Pw[6], 32);
    u32 xp7 = (u32)__shfl_xor((int)Pw[7], 32);
    union { u32 w4[4]; bf16x8 v; } ba, bbu;
    ba.w4[0] = q ? xp2 : Pw[0];
    ba.w4[1] = q ? xp3 : Pw[1];
    ba.w4[2] = q ? Pw[2] : xp0;
    ba.w4[3] = q ? Pw[3] : xp1;
    bbu.w4[0] = q ? xp6 : Pw[4];
    bbu.w4[1] = q ? xp7 : Pw[5];
    bbu.w4[2] = q ? Pw[6] : xp4;
    bbu.w4[3] = q ? Pw[7] : xp5;
    // layer2 (swapped): C2[ch2][j]
    f32x16 c2 = __builtin_amdgcn_mfma_f32_32x32x16_bf16(w2f0, ba.v, b2f, 0, 0, 0);
    c2 = __builtin_amdgcn_mfma_f32_32x32x16_bf16(w2f1, bbu.v, c2, 0, 0, 0);
    // layer3: in-register reduce over own 16 channels + cross-half add
    float acc = 0.f;
    #pragma unroll
    for (int r = 0; r < 16; ++r)
      acc = fmaf(fmaxf(c2[r], 0.f), vw3s[r], acc);
    acc += __shfl_xor(acc, 32);
    if (l < 32 && gi < NN && j0 + o < NN)
      out[((size_t)b * NN + gi) * NN + j0 + o] = acc + b3v;
  }
}

extern "C" void kernel_launch(void* const* d_in, const int* in_sizes, int n_in,
                              void* d_out, int out_size, void* d_ws, size_t ws_size,
                              hipStream_t stream) {
  const float* h_em    = (const float*)d_in[0];
  const float* pos_em  = (const float*)d_in[1];
  const float* Wq_pos  = (const float*)d_in[3];
  const float* Wk_pos  = (const float*)d_in[4];
  const float* Wq_node = (const float*)d_in[5];
  const float* Wk_node = (const float*)d_in[6];
  const float* Pgp     = (const float*)d_in[7];
  const float* Pgn     = (const float*)d_in[8];
  const float* Pnp     = (const float*)d_in[9];
  const float* Pnn     = (const float*)d_in[10];
  const float* W1 = (const float*)d_in[11];
  const float* b1 = (const float*)d_in[12];
  const float* W2 = (const float*)d_in[13];
  const float* b2 = (const float*)d_in[14];
  const float* W3 = (const float*)d_in[15];
  const float* b3 = (const float*)d_in[16];
  float* outp = (float*)d_out;

  float* gp = (float*)d_ws;
  float* gh = gp + BB * DD;
  u16* Qc = (u16*)((char*)d_ws + 16384);
  u16* Kc = Qc + (size_t)BB * NN * QKC;

  hipLaunchKernelGGL(k_graph, dim3(BB), dim3(1024), 0, stream,
                     h_em, pos_em, Pgp, Pgn, gp, gh);
  hipLaunchKernelGGL(k_qk, dim3(BB * NN), dim3(256), 0, stream,
                     h_em, pos_em, Pnp, Pnn, gp, gh,
                     Wq_pos, Wk_pos, Wq_node, Wk_node, Qc, Kc);
  hipLaunchKernelGGL(k_main, dim3(16, 16, BB), dim3(256), 0, stream,
                     Qc, Kc, W1, b1, W2, b2, W3, b3, outp);
}

// Round 6
// 206.746 us; speedup vs baseline: 14.7095x; 1.3401x over previous
//
#include <hip/hip_runtime.h>
#include <hip/hip_bf16.h>

#define BB 16
#define NN 500
#define DD 128
#define QKC 256         // 2 branches * 8 heads * 16 kd

typedef unsigned short u16;
typedef unsigned int u32;
typedef __attribute__((ext_vector_type(8))) short bf16x8;   // MFMA A/B frag
typedef __attribute__((ext_vector_type(16))) float f32x16;  // MFMA C/D frag

// ---- ws layout (bytes) ----
#define MX_OFF   0          // [16 b][2 br][128] f32 = 16384
#define WT_OFF   16384      // 4 mats * (hi 16384 + lo 16384) u16 = 262144
#define PT_OFF   278528     // 2 mats * (hi+lo) = 131072
#define QC_OFF   409600     // 8000*256 u16 = 4096000
#define KC_OFF   4505600    // same

__device__ inline u16 f2bf(float f) {
  __hip_bfloat16 h = __float2bfloat16(f);
  return *(u16*)&h;
}
__device__ inline float bf2f(u16 s) {
  union { u32 u; float f; } uf; uf.u = ((u32)s) << 16; return uf.f;
}

// ================= K_PREP =================
// bid 0..63:  W -> WT[c][k] split hi/lo bf16 (Wq scaled by 0.25 = NORM)
// bid 64..95: P_node -> PT[o][k] split hi/lo
// bid 96..127: per (b,branch) max over N -> mx
__global__ __launch_bounds__(256) void k_prep(
    const float* __restrict__ h_em, const float* __restrict__ pos_em,
    const float* __restrict__ Wq_pos, const float* __restrict__ Wk_pos,
    const float* __restrict__ Wq_node, const float* __restrict__ Wk_node,
    const float* __restrict__ Pnp, const float* __restrict__ Pnn,
    float* __restrict__ mx, u16* __restrict__ wt, u16* __restrict__ pt) {
  int bid = blockIdx.x, t = threadIdx.x;
  __shared__ float smx[2][128];
  if (bid < 64) {
    int task = bid * 256 + t;
    int m = task >> 12, rem = task & 4095;
    int c = rem >> 5, k0 = (rem & 31) * 4;
    const float* src = (m == 0) ? Wq_pos : (m == 1) ? Wk_pos : (m == 2) ? Wq_node : Wk_node;
    float scale = (m & 1) ? 1.f : 0.25f;
    int h = c >> 4, kd = c & 15;
    u16 hs[4], ls[4];
    #pragma unroll
    for (int j = 0; j < 4; ++j) {
      float v = src[h * 2048 + (k0 + j) * 16 + kd] * scale;
      hs[j] = f2bf(v);
      ls[j] = f2bf(v - bf2f(hs[j]));
    }
    u16* dst = wt + m * 32768 + c * 128 + k0;
    *(uint2*)dst = make_uint2((u32)hs[0] | ((u32)hs[1] << 16), (u32)hs[2] | ((u32)hs[3] << 16));
    *(uint2*)(dst + 16384) = make_uint2((u32)ls[0] | ((u32)ls[1] << 16), (u32)ls[2] | ((u32)ls[3] << 16));
  } else if (bid < 96) {
    int task = (bid - 64) * 256 + t;
    int m = task >> 12, rem = task & 4095;
    int o = rem >> 5, k0 = (rem & 31) * 4;
    const float* src = m ? Pnn : Pnp;
    u16 hs[4], ls[4];
    #pragma unroll
    for (int j = 0; j < 4; ++j) {
      float v = src[(k0 + j) * 128 + o];
      hs[j] = f2bf(v);
      ls[j] = f2bf(v - bf2f(hs[j]));
    }
    u16* dst = pt + m * 32768 + o * 128 + k0;
    *(uint2*)dst = make_uint2((u32)hs[0] | ((u32)hs[1] << 16), (u32)hs[2] | ((u32)hs[3] << 16));
    *(uint2*)(dst + 16384) = make_uint2((u32)ls[0] | ((u32)ls[1] << 16), (u32)ls[2] | ((u32)ls[3] << 16));
  } else {
    int id = bid - 96;
    int b = id >> 1, br = id & 1;
    const float* em = br ? h_em : pos_em;
    int d = t & 127, s = t >> 7;
    float v = -1e30f;
    for (int n = s; n < NN; n += 2)
      v = fmaxf(v, em[((size_t)b * NN + n) * DD + d]);
    smx[s][d] = v;
    __syncthreads();
    if (t < 128) mx[(b * 2 + br) * 128 + t] = fmaxf(smx[0][t], smx[1][t]);
  }
}

// ================= K_FUSED =================
// Per block: 64 rows x 1 branch. refine GEMM (split bf16, fp32-accurate) + bias
// -> H in LDS (split) -> Q GEMM -> Qc bf16 -> K GEMM -> Kc bf16.
__global__ __launch_bounds__(256) void k_fused(
    const float* __restrict__ h_em, const float* __restrict__ pos_em,
    const float* __restrict__ Pgp, const float* __restrict__ Pgn,
    const float* __restrict__ mx, const u16* __restrict__ wt, const u16* __restrict__ pt,
    u16* __restrict__ Qc, u16* __restrict__ Kc) {
  __shared__ __align__(16) char sm[99328];
  u16* Ah = (u16*)sm;             // [64][128] swizzled: slot ^ (row&15)
  u16* Al = (u16*)(sm + 16384);
  u16* Bh = (u16*)(sm + 32768);   // [128][128]
  u16* Bl = (u16*)(sm + 65536);
  float* gld = (float*)(sm + 98304);  // [2][128] graph bias
  int t = threadIdx.x, l = t & 63, w = t >> 6, o = l & 31, q = l >> 5;
  int r0 = blockIdx.x * 64, br = blockIdx.y;
  const float* em = br ? h_em : pos_em;
  int b0 = r0 / NN;
  // phase 0: graph bias for the (up to) 2 batches this tile spans
  {
    int bx = t >> 7, oo = t & 127;
    int be = min(b0 + bx, BB - 1);
    const float* Pg = br ? Pgn : Pgp;
    const float* m = mx + (be * 2 + br) * 128;
    float a = 0.f;
    #pragma unroll 8
    for (int k = 0; k < 128; ++k) a = fmaf(m[k], Pg[k * 128 + oo], a);
    gld[bx * 128 + oo] = a;
  }
  // stage X (split) into A
  #pragma unroll
  for (int it = 0; it < 8; ++it) {
    int idx = it * 256 + t;
    int row = idx >> 5, c4 = idx & 31;
    float4 v = *(const float4*)(em + (size_t)(r0 + row) * 128 + c4 * 4);
    u16 hs[4], ls[4];
    float vv[4] = {v.x, v.y, v.z, v.w};
    #pragma unroll
    for (int j = 0; j < 4; ++j) { hs[j] = f2bf(vv[j]); ls[j] = f2bf(vv[j] - bf2f(hs[j])); }
    int off = row * 128 + (((c4 >> 1) ^ (row & 15)) << 3) + ((c4 & 1) << 2);
    *(uint2*)(Ah + off) = make_uint2((u32)hs[0] | ((u32)hs[1] << 16), (u32)hs[2] | ((u32)hs[3] << 16));
    *(uint2*)(Al + off) = make_uint2((u32)ls[0] | ((u32)ls[1] << 16), (u32)ls[2] | ((u32)ls[3] << 16));
  }
  // stage PT (refine weight, pre-split) into B
  {
    const u16* ptm = pt + br * 32768;
    #pragma unroll
    for (int it = 0; it < 8; ++it) {
      int idx = it * 256 + t;
      int c = idx >> 4, s = idx & 15;
      uint4 vh = *(const uint4*)(ptm + c * 128 + s * 8);
      uint4 vl = *(const uint4*)(ptm + 16384 + c * 128 + s * 8);
      int ss = s ^ (c & 15);
      *(uint4*)(Bh + c * 128 + ss * 8) = vh;
      *(uint4*)(Bl + c * 128 + ss * 8) = vl;
    }
  }
  __syncthreads();
  int rt = w & 1, cb = (w >> 1) * 2;
  int colA = cb * 32 + o, colB = (cb + 1) * 32 + o;
  // refine GEMM: H = X @ P (3-term split)
  f32x16 C0, C1;
  #pragma unroll
  for (int r = 0; r < 16; ++r) { C0[r] = 0.f; C1[r] = 0.f; }
  #pragma unroll
  for (int kk = 0; kk < 8; ++kk) {
    int arow = rt * 32 + o;
    int sl = 2 * kk + q;
    bf16x8 ah = *(const bf16x8*)(Ah + arow * 128 + ((sl ^ (arow & 15)) << 3));
    bf16x8 al = *(const bf16x8*)(Al + arow * 128 + ((sl ^ (arow & 15)) << 3));
    bf16x8 bh0 = *(const bf16x8*)(Bh + colA * 128 + ((sl ^ (colA & 15)) << 3));
    bf16x8 bl0 = *(const bf16x8*)(Bl + colA * 128 + ((sl ^ (colA & 15)) << 3));
    bf16x8 bh1 = *(const bf16x8*)(Bh + colB * 128 + ((sl ^ (colB & 15)) << 3));
    bf16x8 bl1 = *(const bf16x8*)(Bl + colB * 128 + ((sl ^ (colB & 15)) << 3));
    C0 = __builtin_amdgcn_mfma_f32_32x32x16_bf16(ah, bh0, C0, 0, 0, 0);
    C0 = __builtin_amdgcn_mfma_f32_32x32x16_bf16(al, bh0, C0, 0, 0, 0);
    C0 = __builtin_amdgcn_mfma_f32_32x32x16_bf16(ah, bl0, C0, 0, 0, 0);
    C1 = __builtin_amdgcn_mfma_f32_32x32x16_bf16(ah, bh1, C1, 0, 0, 0);
    C1 = __builtin_amdgcn_mfma_f32_32x32x16_bf16(al, bh1, C1, 0, 0, 0);
    C1 = __builtin_amdgcn_mfma_f32_32x32x16_bf16(ah, bl1, C1, 0, 0, 0);
  }
  __syncthreads();
  // write H (+ bias) split into A (X dead)
  {
    int bsplit = (b0 + 1) * NN - r0;
    float gA0 = gld[colA], gA1 = gld[128 + colA];
    float gB0 = gld[colB], gB1 = gld[128 + colB];
    #pragma unroll
    for (int r = 0; r < 16; ++r) {
      int rl_ = (r & 3) + 8 * (r >> 2) + 4 * q;
      int row = rt * 32 + rl_;
      bool s2 = row >= bsplit;
      float vA = C0[r] + (s2 ? gA1 : gA0);
      float vB = C1[r] + (s2 ? gB1 : gB0);
      u16 hA = f2bf(vA), hB = f2bf(vB);
      u16 lA = f2bf(vA - bf2f(hA)), lB = f2bf(vB - bf2f(hB));
      int oA = row * 128 + ((((colA >> 3) ^ (row & 15))) << 3) + (o & 7);
      int oB = row * 128 + ((((colB >> 3) ^ (row & 15))) << 3) + (o & 7);
      Ah[oA] = hA; Al[oA] = lA;
      Ah[oB] = hB; Al[oB] = lB;
    }
  }
  // stage WQ^T into B (B dead after refine GEMM)
  {
    const u16* wm = wt + (br * 2 + 0) * 32768;
    #pragma unroll
    for (int it = 0; it < 8; ++it) {
      int idx = it * 256 + t;
      int c = idx >> 4, s = idx & 15;
      uint4 vh = *(const uint4*)(wm + c * 128 + s * 8);
      uint4 vl = *(const uint4*)(wm + 16384 + c * 128 + s * 8);
      int ss = s ^ (c & 15);
      *(uint4*)(Bh + c * 128 + ss * 8) = vh;
      *(uint4*)(Bl + c * 128 + ss * 8) = vl;
    }
  }
  __syncthreads();
  // Q GEMM + store, then K
  #pragma unroll 1
  for (int qk = 0; qk < 2; ++qk) {
    f32x16 Q0, Q1;
    #pragma unroll
    for (int r = 0; r < 16; ++r) { Q0[r] = 0.f; Q1[r] = 0.f; }
    #pragma unroll
    for (int kk = 0; kk < 8; ++kk) {
      int arow = rt * 32 + o;
      int sl = 2 * kk + q;
      bf16x8 ah = *(const bf16x8*)(Ah + arow * 128 + ((sl ^ (arow & 15)) << 3));
      bf16x8 al = *(const bf16x8*)(Al + arow * 128 + ((sl ^ (arow & 15)) << 3));
      bf16x8 bh0 = *(const bf16x8*)(Bh + colA * 128 + ((sl ^ (colA & 15)) << 3));
      bf16x8 bl0 = *(const bf16x8*)(Bl + colA * 128 + ((sl ^ (colA & 15)) << 3));
      bf16x8 bh1 = *(const bf16x8*)(Bh + colB * 128 + ((sl ^ (colB & 15)) << 3));
      bf16x8 bl1 = *(const bf16x8*)(Bl + colB * 128 + ((sl ^ (colB & 15)) << 3));
      Q0 = __builtin_amdgcn_mfma_f32_32x32x16_bf16(ah, bh0, Q0, 0, 0, 0);
      Q0 = __builtin_amdgcn_mfma_f32_32x32x16_bf16(al, bh0, Q0, 0, 0, 0);
      Q0 = __builtin_amdgcn_mfma_f32_32x32x16_bf16(ah, bl0, Q0, 0, 0, 0);
      Q1 = __builtin_amdgcn_mfma_f32_32x32x16_bf16(ah, bh1, Q1, 0, 0, 0);
      Q1 = __builtin_amdgcn_mfma_f32_32x32x16_bf16(al, bh1, Q1, 0, 0, 0);
      Q1 = __builtin_amdgcn_mfma_f32_32x32x16_bf16(ah, bl1, Q1, 0, 0, 0);
    }
    u16* dst = qk ? Kc : Qc;
    #pragma unroll
    for (int r = 0; r < 16; ++r) {
      int rl_ = (r & 3) + 8 * (r >> 2) + 4 * q;
      size_t bn = r0 + rt * 32 + rl_;
      dst[bn * QKC + br * 128 + colA] = f2bf(Q0[r]);
      dst[bn * QKC + br * 128 + colB] = f2bf(Q1[r]);
    }
    if (qk == 0) {
      __syncthreads();
      const u16* wm = wt + (br * 2 + 1) * 32768;
      #pragma unroll
      for (int it = 0; it < 8; ++it) {
        int idx = it * 256 + t;
        int c = idx >> 4, s = idx & 15;
        uint4 vh = *(const uint4*)(wm + c * 128 + s * 8);
        uint4 vl = *(const uint4*)(wm + 16384 + c * 128 + s * 8);
        int ss = s ^ (c & 15);
        *(uint4*)(Bh + c * 128 + ss * 8) = vh;
        *(uint4*)(Bl + c * 128 + ss * 8) = vl;
      }
      __syncthreads();
    }
  }
}

// ===== K3 (round-5 proven, verbatim): MFMA compat + register MLP =====
__global__ __launch_bounds__(256) void k_main(
    const u16* __restrict__ Qc, const u16* __restrict__ Kc,
    const float* __restrict__ W1, const float* __restrict__ b1,
    const float* __restrict__ W2, const float* __restrict__ b2,
    const float* __restrict__ W3, const float* __restrict__ b3,
    float* __restrict__ out) {
  __shared__ __align__(16) char sm[81920];
  u16* Qt = (u16*)sm;             // [32][256] swizzled slot ^ row
  u16* Kt = (u16*)(sm + 16384);
  u16* CM = (u16*)(sm + 32768);   // [32 i][32 j][24] (16 ch + 8 pad)
  int t = threadIdx.x, l = t & 63, w = t >> 6, o = l & 31, q = l >> 5;
  int b = blockIdx.z, i0 = blockIdx.y * 32, j0 = blockIdx.x * 32;

  bf16x8 w1f, w2f0, w2f1;
  #pragma unroll
  for (int e = 0; e < 8; ++e) {
    w1f[e]  = (short)f2bf(W1[(8 * q + e) * 32 + o]);
    w2f0[e] = (short)f2bf(W2[(8 * q + e) * 32 + o]);
    w2f1[e] = (short)f2bf(W2[(16 + 8 * q + e) * 32 + o]);
  }
  f32x16 b1f, b2f;
  float vw3s[16];
  #pragma unroll
  for (int r = 0; r < 16; ++r) {
    int ch = (r & 3) + 8 * (r >> 2) + 4 * q;
    b1f[r] = b1[ch]; b2f[r] = b2[ch]; vw3s[r] = W3[ch];
  }
  float b3v = b3[0];

  #pragma unroll
  for (int rep = 0; rep < 4; ++rep) {
    int s = t + rep * 256;
    int r = s >> 5, c = s & 31;
    int gi = i0 + r; if (gi >= NN) gi = NN - 1;
    int gj = j0 + r; if (gj >= NN) gj = NN - 1;
    uint4 qv = *(const uint4*)(Qc + ((size_t)b * NN + gi) * QKC + c * 8);
    uint4 kv = *(const uint4*)(Kc + ((size_t)b * NN + gj) * QKC + c * 8);
    int cs = c ^ r;
    *(uint4*)(Qt + r * 256 + cs * 8) = qv;
    *(uint4*)(Kt + r * 256 + cs * 8) = kv;
  }
  __syncthreads();

  {
    f32x16 cz;
    #pragma unroll
    for (int r = 0; r < 16; ++r) cz[r] = 0.f;
    f32x16 cc[4];
    #pragma unroll
    for (int m = 0; m < 4; ++m) {
      int ch = 4 * w + m;
      int slot = (2 * ch + q) ^ o;
      bf16x8 a  = *(const bf16x8*)(Qt + o * 256 + slot * 8);
      bf16x8 bb = *(const bf16x8*)(Kt + o * 256 + slot * 8);
      cc[m] = __builtin_amdgcn_mfma_f32_32x32x16_bf16(a, bb, cz, 0, 0, 0);
    }
    #pragma unroll
    for (int r = 0; r < 16; ++r) {
      int i = (r & 3) + 8 * (r >> 2) + 4 * q;
      u32 d0 = (u32)f2bf(cc[0][r]) | ((u32)f2bf(cc[1][r]) << 16);
      u32 d1 = (u32)f2bf(cc[2][r]) | ((u32)f2bf(cc[3][r]) << 16);
      *(uint2*)(CM + i * 768 + o * 24 + 4 * w) = make_uint2(d0, d1);
    }
  }
  __syncthreads();

  #pragma unroll 1
  for (int s = 0; s < 8; ++s) {
    int i = 8 * w + s;
    int gi = i0 + i;
    bf16x8 a1 = *(const bf16x8*)(CM + i * 768 + o * 24 + 8 * q);
    f32x16 c1 = __builtin_amdgcn_mfma_f32_32x32x16_bf16(w1f, a1, b1f, 0, 0, 0);
    u32 Pw[8];
    #pragma unroll
    for (int g = 0; g < 4; ++g) {
      #pragma unroll
      for (int ww = 0; ww < 2; ++ww) {
        float x0 = fmaxf(c1[4 * g + 2 * ww], 0.f);
        float x1 = fmaxf(c1[4 * g + 2 * ww + 1], 0.f);
        Pw[g * 2 + ww] = (u32)f2bf(x0) | ((u32)f2bf(x1) << 16);
      }
    }
    u32 xp0 = (u32)__shfl_xor((int)Pw[0], 32);
    u32 xp1 = (u32)__shfl_xor((int)Pw[1], 32);
    u32 xp2 = (u32)__shfl_xor((int)Pw[2], 32);
    u32 xp3 = (u32)__shfl_xor((int)Pw[3], 32);
    u32 xp4 = (u32)__shfl_xor((int)Pw[4], 32);
    u32 xp5 = (u32)__shfl_xor((int)Pw[5], 32);
    u32 xp6 = (u32)__shfl_xor((int)Pw[6], 32);
    u32 xp7 = (u32)__shfl_xor((int)Pw[7], 32);
    union { u32 w4[4]; bf16x8 v; } ba, bbu;
    ba.w4[0] = q ? xp2 : Pw[0];
    ba.w4[1] = q ? xp3 : Pw[1];
    ba.w4[2] = q ? Pw[2] : xp0;
    ba.w4[3] = q ? Pw[3] : xp1;
    bbu.w4[0] = q ? xp6 : Pw[4];
    bbu.w4[1] = q ? xp7 : Pw[5];
    bbu.w4[2] = q ? Pw[6] : xp4;
    bbu.w4[3] = q ? Pw[7] : xp5;
    f32x16 c2 = __builtin_amdgcn_mfma_f32_32x32x16_bf16(w2f0, ba.v, b2f, 0, 0, 0);
    c2 = __builtin_amdgcn_mfma_f32_32x32x16_bf16(w2f1, bbu.v, c2, 0, 0, 0);
    float acc = 0.f;
    #pragma unroll
    for (int r = 0; r < 16; ++r)
      acc = fmaf(fmaxf(c2[r], 0.f), vw3s[r], acc);
    acc += __shfl_xor(acc, 32);
    if (l < 32 && gi < NN && j0 + o < NN)
      out[((size_t)b * NN + gi) * NN + j0 + o] = acc + b3v;
  }
}

extern "C" void kernel_launch(void* const* d_in, const int* in_sizes, int n_in,
                              void* d_out, int out_size, void* d_ws, size_t ws_size,
                              hipStream_t stream) {
  const float* h_em    = (const float*)d_in[0];
  const float* pos_em  = (const float*)d_in[1];
  const float* Wq_pos  = (const float*)d_in[3];
  const float* Wk_pos  = (const float*)d_in[4];
  const float* Wq_node = (const float*)d_in[5];
  const float* Wk_node = (const float*)d_in[6];
  const float* Pgp     = (const float*)d_in[7];
  const float* Pgn     = (const float*)d_in[8];
  const float* Pnp     = (const float*)d_in[9];
  const float* Pnn     = (const float*)d_in[10];
  const float* W1 = (const float*)d_in[11];
  const float* b1 = (const float*)d_in[12];
  const float* W2 = (const float*)d_in[13];
  const float* b2 = (const float*)d_in[14];
  const float* W3 = (const float*)d_in[15];
  const float* b3 = (const float*)d_in[16];
  float* outp = (float*)d_out;

  char* ws = (char*)d_ws;
  float* mxp = (float*)(ws + MX_OFF);
  u16* wt = (u16*)(ws + WT_OFF);
  u16* pt = (u16*)(ws + PT_OFF);
  u16* Qc = (u16*)(ws + QC_OFF);
  u16* Kc = (u16*)(ws + KC_OFF);

  hipLaunchKernelGGL(k_prep, dim3(128), dim3(256), 0, stream,
                     h_em, pos_em, Wq_pos, Wk_pos, Wq_node, Wk_node,
                     Pnp, Pnn, mxp, wt, pt);
  hipLaunchKernelGGL(k_fused, dim3(125, 2), dim3(256), 0, stream,
                     h_em, pos_em, Pgp, Pgn, mxp, wt, pt, Qc, Kc);
  hipLaunchKernelGGL(k_main, dim3(16, 16, BB), dim3(256), 0, stream,
                     Qc, Kc, W1, b1, W2, b2, W3, b3, outp);
}

// Round 7
// 195.336 us; speedup vs baseline: 15.5686x; 1.0584x over previous
//
#include <hip/hip_runtime.h>
#include <hip/hip_bf16.h>

#define BB 16
#define NN 500
#define DD 128
#define QKC 256         // 2 branches * 8 heads * 16 kd

typedef unsigned short u16;
typedef unsigned int u32;
typedef __attribute__((ext_vector_type(8))) short bf16x8;   // MFMA A/B frag
typedef __attribute__((ext_vector_type(16))) float f32x16;  // MFMA C/D frag

// ---- ws layout (bytes) ----
#define GB_OFF   0          // gbias [16 b][2 br][128] f32 = 16384
#define WT_OFF   16384      // 4 mats * (hi 16384 + lo 16384) u16 = 262144
#define PT_OFF   278528     // 2 mats * (hi+lo) = 131072
#define QC_OFF   409600     // 8000*256 u16 = 4096000
#define KC_OFF   4505600    // same

__device__ inline u16 f2bf(float f) {
  __hip_bfloat16 h = __float2bfloat16(f);
  return *(u16*)&h;
}
__device__ inline float bf2f(u16 s) {
  union { u32 u; float f; } uf; uf.u = ((u32)s) << 16; return uf.f;
}

// ================= K_PREP =================
// bid 0..63:  W -> WT[c][k] split hi/lo bf16 (Wq scaled by 0.25 = NORM)
// bid 64..95: P_node -> PT[o][k] split hi/lo
// bid 96..127: per (b,branch): max over N, then graph bias = mx @ Pg -> gbias
__global__ __launch_bounds__(256) void k_prep(
    const float* __restrict__ h_em, const float* __restrict__ pos_em,
    const float* __restrict__ Wq_pos, const float* __restrict__ Wk_pos,
    const float* __restrict__ Wq_node, const float* __restrict__ Wk_node,
    const float* __restrict__ Pnp, const float* __restrict__ Pnn,
    const float* __restrict__ Pgp, const float* __restrict__ Pgn,
    float* __restrict__ gbias, u16* __restrict__ wt, u16* __restrict__ pt) {
  int bid = blockIdx.x, t = threadIdx.x;
  __shared__ float smx[2][128];
  if (bid < 64) {
    int task = bid * 256 + t;
    int m = task >> 12, rem = task & 4095;
    int c = rem >> 5, k0 = (rem & 31) * 4;
    const float* src = (m == 0) ? Wq_pos : (m == 1) ? Wk_pos : (m == 2) ? Wq_node : Wk_node;
    float scale = (m & 1) ? 1.f : 0.25f;
    int h = c >> 4, kd = c & 15;
    u16 hs[4], ls[4];
    #pragma unroll
    for (int j = 0; j < 4; ++j) {
      float v = src[h * 2048 + (k0 + j) * 16 + kd] * scale;
      hs[j] = f2bf(v);
      ls[j] = f2bf(v - bf2f(hs[j]));
    }
    u16* dst = wt + m * 32768 + c * 128 + k0;
    *(uint2*)dst = make_uint2((u32)hs[0] | ((u32)hs[1] << 16), (u32)hs[2] | ((u32)hs[3] << 16));
    *(uint2*)(dst + 16384) = make_uint2((u32)ls[0] | ((u32)ls[1] << 16), (u32)ls[2] | ((u32)ls[3] << 16));
  } else if (bid < 96) {
    int task = (bid - 64) * 256 + t;
    int m = task >> 12, rem = task & 4095;
    int o = rem >> 5, k0 = (rem & 31) * 4;
    const float* src = m ? Pnn : Pnp;
    u16 hs[4], ls[4];
    #pragma unroll
    for (int j = 0; j < 4; ++j) {
      float v = src[(k0 + j) * 128 + o];
      hs[j] = f2bf(v);
      ls[j] = f2bf(v - bf2f(hs[j]));
    }
    u16* dst = pt + m * 32768 + o * 128 + k0;
    *(uint2*)dst = make_uint2((u32)hs[0] | ((u32)hs[1] << 16), (u32)hs[2] | ((u32)hs[3] << 16));
    *(uint2*)(dst + 16384) = make_uint2((u32)ls[0] | ((u32)ls[1] << 16), (u32)ls[2] | ((u32)ls[3] << 16));
  } else {
    int id = bid - 96;
    int b = id >> 1, br = id & 1;
    const float* em = br ? h_em : pos_em;
    const float* Pg = br ? Pgn : Pgp;
    int d = t & 127, s = t >> 7;
    float v = -1e30f;
    for (int n = s; n < NN; n += 2)
      v = fmaxf(v, em[((size_t)b * NN + n) * DD + d]);
    smx[s][d] = v;
    __syncthreads();
    if (t < 128) smx[0][t] = fmaxf(smx[0][t], smx[1][t]);
    __syncthreads();
    if (t < 128) {
      float a = 0.f;
      #pragma unroll 8
      for (int k = 0; k < 128; ++k) a = fmaf(smx[0][k], Pg[k * 128 + t], a);
      gbias[(b * 2 + br) * 128 + t] = a;
    }
  }
}

// ================= K_FUSED =================
// Per block: 32 rows x 1 branch (grid 250x2 -> rows tile exactly, no clamps).
// refine GEMM (split bf16) + gbias -> H in LDS (split) -> Q GEMM -> K GEMM.
// LDS exactly 80 KB -> 2 blocks/CU.
__global__ __launch_bounds__(256) void k_fused(
    const float* __restrict__ h_em, const float* __restrict__ pos_em,
    const float* __restrict__ gbias, const u16* __restrict__ wt, const u16* __restrict__ pt,
    u16* __restrict__ Qc, u16* __restrict__ Kc) {
  __shared__ __align__(16) char sm[81920];
  u16* Ah = (u16*)sm;             // [32][128] swizzled: slot ^ (row&15)
  u16* Al = (u16*)(sm + 8192);
  u16* Bh = (u16*)(sm + 16384);   // [128][128]
  u16* Bl = (u16*)(sm + 49152);
  int t = threadIdx.x, l = t & 63, w = t >> 6, o = l & 31, q = l >> 5;
  int r0 = blockIdx.x * 32, br = blockIdx.y;
  const float* em = br ? h_em : pos_em;
  int b0 = r0 / NN;
  int bsplit = (b0 + 1) * NN - r0;          // rows >= bsplit belong to b0+1
  int be = min(b0 + 1, BB - 1);
  int col = w * 32 + o;                     // each wave owns one 32-col tile
  float gA0 = gbias[(b0 * 2 + br) * 128 + col];
  float gA1 = gbias[(be * 2 + br) * 128 + col];
  // stage X (split) into A: 32x128 = 1024 float4 / 256 thr = 4 iters
  #pragma unroll
  for (int it = 0; it < 4; ++it) {
    int idx = it * 256 + t;
    int row = idx >> 5, c4 = idx & 31;
    float4 v = *(const float4*)(em + (size_t)(r0 + row) * 128 + c4 * 4);
    u16 hs[4], ls[4];
    float vv[4] = {v.x, v.y, v.z, v.w};
    #pragma unroll
    for (int j = 0; j < 4; ++j) { hs[j] = f2bf(vv[j]); ls[j] = f2bf(vv[j] - bf2f(hs[j])); }
    int off = row * 128 + (((c4 >> 1) ^ (row & 15)) << 3) + ((c4 & 1) << 2);
    *(uint2*)(Ah + off) = make_uint2((u32)hs[0] | ((u32)hs[1] << 16), (u32)hs[2] | ((u32)hs[3] << 16));
    *(uint2*)(Al + off) = make_uint2((u32)ls[0] | ((u32)ls[1] << 16), (u32)ls[2] | ((u32)ls[3] << 16));
  }
  // stage PT (refine weight, pre-split) into B
  {
    const u16* ptm = pt + br * 32768;
    #pragma unroll
    for (int it = 0; it < 8; ++it) {
      int idx = it * 256 + t;
      int c = idx >> 4, s = idx & 15;
      uint4 vh = *(const uint4*)(ptm + c * 128 + s * 8);
      uint4 vl = *(const uint4*)(ptm + 16384 + c * 128 + s * 8);
      int ss = s ^ (c & 15);
      *(uint4*)(Bh + c * 128 + ss * 8) = vh;
      *(uint4*)(Bl + c * 128 + ss * 8) = vl;
    }
  }
  __syncthreads();
  // refine GEMM: H = X @ P (3-term split), one C-frag per wave
  f32x16 C0;
  #pragma unroll
  for (int r = 0; r < 16; ++r) C0[r] = 0.f;
  #pragma unroll
  for (int kk = 0; kk < 8; ++kk) {
    int sl = 2 * kk + q;
    bf16x8 ah = *(const bf16x8*)(Ah + o * 128 + ((sl ^ (o & 15)) << 3));
    bf16x8 al = *(const bf16x8*)(Al + o * 128 + ((sl ^ (o & 15)) << 3));
    bf16x8 bh0 = *(const bf16x8*)(Bh + col * 128 + ((sl ^ (col & 15)) << 3));
    bf16x8 bl0 = *(const bf16x8*)(Bl + col * 128 + ((sl ^ (col & 15)) << 3));
    C0 = __builtin_amdgcn_mfma_f32_32x32x16_bf16(ah, bh0, C0, 0, 0, 0);
    C0 = __builtin_amdgcn_mfma_f32_32x32x16_bf16(al, bh0, C0, 0, 0, 0);
    C0 = __builtin_amdgcn_mfma_f32_32x32x16_bf16(ah, bl0, C0, 0, 0, 0);
  }
  __syncthreads();
  // write H (+ bias) split into A (X dead)
  #pragma unroll
  for (int r = 0; r < 16; ++r) {
    int row = (r & 3) + 8 * (r >> 2) + 4 * q;
    float vA = C0[r] + (row >= bsplit ? gA1 : gA0);
    u16 hA = f2bf(vA);
    u16 lA = f2bf(vA - bf2f(hA));
    int oA = row * 128 + ((((col >> 3) ^ (row & 15))) << 3) + (o & 7);
    Ah[oA] = hA; Al[oA] = lA;
  }
  // stage WQ^T into B (B dead after refine GEMM)
  {
    const u16* wm = wt + (br * 2 + 0) * 32768;
    #pragma unroll
    for (int it = 0; it < 8; ++it) {
      int idx = it * 256 + t;
      int c = idx >> 4, s = idx & 15;
      uint4 vh = *(const uint4*)(wm + c * 128 + s * 8);
      uint4 vl = *(const uint4*)(wm + 16384 + c * 128 + s * 8);
      int ss = s ^ (c & 15);
      *(uint4*)(Bh + c * 128 + ss * 8) = vh;
      *(uint4*)(Bl + c * 128 + ss * 8) = vl;
    }
  }
  __syncthreads();
  // Q GEMM + store, then K
  #pragma unroll 1
  for (int qk = 0; qk < 2; ++qk) {
    f32x16 Q0;
    #pragma unroll
    for (int r = 0; r < 16; ++r) Q0[r] = 0.f;
    #pragma unroll
    for (int kk = 0; kk < 8; ++kk) {
      int sl = 2 * kk + q;
      bf16x8 ah = *(const bf16x8*)(Ah + o * 128 + ((sl ^ (o & 15)) << 3));
      bf16x8 al = *(const bf16x8*)(Al + o * 128 + ((sl ^ (o & 15)) << 3));
      bf16x8 bh0 = *(const bf16x8*)(Bh + col * 128 + ((sl ^ (col & 15)) << 3));
      bf16x8 bl0 = *(const bf16x8*)(Bl + col * 128 + ((sl ^ (col & 15)) << 3));
      Q0 = __builtin_amdgcn_mfma_f32_32x32x16_bf16(ah, bh0, Q0, 0, 0, 0);
      Q0 = __builtin_amdgcn_mfma_f32_32x32x16_bf16(al, bh0, Q0, 0, 0, 0);
      Q0 = __builtin_amdgcn_mfma_f32_32x32x16_bf16(ah, bl0, Q0, 0, 0, 0);
    }
    u16* dst = qk ? Kc : Qc;
    #pragma unroll
    for (int r = 0; r < 16; ++r) {
      int rl_ = (r & 3) + 8 * (r >> 2) + 4 * q;
      dst[(size_t)(r0 + rl_) * QKC + br * 128 + col] = f2bf(Q0[r]);
    }
    if (qk == 0) {
      __syncthreads();
      const u16* wm = wt + (br * 2 + 1) * 32768;
      #pragma unroll
      for (int it = 0; it < 8; ++it) {
        int idx = it * 256 + t;
        int c = idx >> 4, s = idx & 15;
        uint4 vh = *(const uint4*)(wm + c * 128 + s * 8);
        uint4 vl = *(const uint4*)(wm + 16384 + c * 128 + s * 8);
        int ss = s ^ (c & 15);
        *(uint4*)(Bh + c * 128 + ss * 8) = vh;
        *(uint4*)(Bl + c * 128 + ss * 8) = vl;
      }
      __syncthreads();
    }
  }
}

// ================= K_MAIN =================
// 32x32 pair tile per block. Compat A/B frags read DIRECTLY from global
// (L2-resident Qc/Kc) -> CM LDS (48KB only -> 3 blocks/CU). MLP in registers;
// layer1->layer2 transpose eliminated via sigma-permuted W2 rows:
//   sigma1(q,e) = 8*(e>>2) + 4*q + (e&3); layer-2 B-frag = cvt_pk(c1[0..7]) pairs.
__global__ __launch_bounds__(256) void k_main(
    const u16* __restrict__ Qc, const u16* __restrict__ Kc,
    const float* __restrict__ W1, const float* __restrict__ b1,
    const float* __restrict__ W2, const float* __restrict__ b2,
    const float* __restrict__ W3, const float* __restrict__ b3,
    float* __restrict__ out) {
  __shared__ __align__(16) char sm[49152];
  u16* CM = (u16*)sm;             // [32 i][32 j][24] (16 ch + 8 pad)
  int t = threadIdx.x, l = t & 63, w = t >> 6, o = l & 31, q = l >> 5;
  int b = blockIdx.z, i0 = blockIdx.y * 32, j0 = blockIdx.x * 32;

  // weight frags: layer1 A = W1^T (natural order); layer2 A = W2^T sigma-permuted
  bf16x8 w1f, w2f0, w2f1;
  #pragma unroll
  for (int e = 0; e < 8; ++e) {
    int s1 = 8 * (e >> 2) + 4 * q + (e & 3);
    w1f[e]  = (short)f2bf(W1[(8 * q + e) * 32 + o]);
    w2f0[e] = (short)f2bf(W2[s1 * 32 + o]);
    w2f1[e] = (short)f2bf(W2[(16 + s1) * 32 + o]);
  }
  f32x16 b1f, b2f;
  float vw3s[16];
  #pragma unroll
  for (int r = 0; r < 16; ++r) {
    int ch = (r & 3) + 8 * (r >> 2) + 4 * q;
    b1f[r] = b1[ch]; b2f[r] = b2[ch]; vw3s[r] = W3[ch];
  }
  float b3v = b3[0];

  // compat: wave w -> channels 4w..4w+3; frags direct from global
  int gi = i0 + o; if (gi >= NN) gi = NN - 1;
  int gj = j0 + o; if (gj >= NN) gj = NN - 1;
  const u16* qrow = Qc + ((size_t)b * NN + gi) * QKC + q * 8;
  const u16* krow = Kc + ((size_t)b * NN + gj) * QKC + q * 8;
  {
    f32x16 cz;
    #pragma unroll
    for (int r = 0; r < 16; ++r) cz[r] = 0.f;
    f32x16 cc[4];
    #pragma unroll
    for (int m = 0; m < 4; ++m) {
      int ch = 4 * w + m;
      bf16x8 a  = *(const bf16x8*)(qrow + ch * 16);
      bf16x8 bb = *(const bf16x8*)(krow + ch * 16);
      cc[m] = __builtin_amdgcn_mfma_f32_32x32x16_bf16(a, bb, cz, 0, 0, 0);
    }
    #pragma unroll
    for (int r = 0; r < 16; ++r) {
      int i = (r & 3) + 8 * (r >> 2) + 4 * q;
      u32 d0 = (u32)f2bf(cc[0][r]) | ((u32)f2bf(cc[1][r]) << 16);
      u32 d1 = (u32)f2bf(cc[2][r]) | ((u32)f2bf(cc[3][r]) << 16);
      *(uint2*)(CM + i * 768 + o * 24 + 4 * w) = make_uint2(d0, d1);
    }
  }
  __syncthreads();

  // MLP: wave w owns i = 8w..8w+7; fully in registers, zero shuffles
  #pragma unroll 1
  for (int s = 0; s < 8; ++s) {
    int i = 8 * w + s;
    int gis = i0 + i;
    bf16x8 a1 = *(const bf16x8*)(CM + i * 768 + o * 24 + 8 * q);
    f32x16 c1 = __builtin_amdgcn_mfma_f32_32x32x16_bf16(w1f, a1, b1f, 0, 0, 0);
    union { u32 w4[4]; bf16x8 v; } ba, bbu;
    #pragma unroll
    for (int p = 0; p < 4; ++p) {
      ba.w4[p]  = (u32)f2bf(fmaxf(c1[2 * p], 0.f))     | ((u32)f2bf(fmaxf(c1[2 * p + 1], 0.f)) << 16);
      bbu.w4[p] = (u32)f2bf(fmaxf(c1[8 + 2 * p], 0.f)) | ((u32)f2bf(fmaxf(c1[8 + 2 * p + 1], 0.f)) << 16);
    }
    f32x16 c2 = __builtin_amdgcn_mfma_f32_32x32x16_bf16(w2f0, ba.v, b2f, 0, 0, 0);
    c2 = __builtin_amdgcn_mfma_f32_32x32x16_bf16(w2f1, bbu.v, c2, 0, 0, 0);
    float acc = 0.f;
    #pragma unroll
    for (int r = 0; r < 16; ++r)
      acc = fmaf(fmaxf(c2[r], 0.f), vw3s[r], acc);
    acc += __shfl_xor(acc, 32);
    if (l < 32 && gis < NN && j0 + o < NN)
      out[((size_t)b * NN + gis) * NN + j0 + o] = acc + b3v;
  }
}

extern "C" void kernel_launch(void* const* d_in, const int* in_sizes, int n_in,
                              void* d_out, int out_size, void* d_ws, size_t ws_size,
                              hipStream_t stream) {
  const float* h_em    = (const float*)d_in[0];
  const float* pos_em  = (const float*)d_in[1];
  const float* Wq_pos  = (const float*)d_in[3];
  const float* Wk_pos  = (const float*)d_in[4];
  const float* Wq_node = (const float*)d_in[5];
  const float* Wk_node = (const float*)d_in[6];
  const float* Pgp     = (const float*)d_in[7];
  const float* Pgn     = (const float*)d_in[8];
  const float* Pnp     = (const float*)d_in[9];
  const float* Pnn     = (const float*)d_in[10];
  const float* W1 = (const float*)d_in[11];
  const float* b1 = (const float*)d_in[12];
  const float* W2 = (const float*)d_in[13];
  const float* b2 = (const float*)d_in[14];
  const float* W3 = (const float*)d_in[15];
  const float* b3 = (const float*)d_in[16];
  float* outp = (float*)d_out;

  char* ws = (char*)d_ws;
  float* gbias = (float*)(ws + GB_OFF);
  u16* wt = (u16*)(ws + WT_OFF);
  u16* pt = (u16*)(ws + PT_OFF);
  u16* Qc = (u16*)(ws + QC_OFF);
  u16* Kc = (u16*)(ws + KC_OFF);

  hipLaunchKernelGGL(k_prep, dim3(128), dim3(256), 0, stream,
                     h_em, pos_em, Wq_pos, Wk_pos, Wq_node, Wk_node,
                     Pnp, Pnn, Pgp, Pgn, gbias, wt, pt);
  hipLaunchKernelGGL(k_fused, dim3(250, 2), dim3(256), 0, stream,
                     h_em, pos_em, gbias, wt, pt, Qc, Kc);
  hipLaunchKernelGGL(k_main, dim3(16, 16, BB), dim3(256), 0, stream,
                     Qc, Kc, W1, b1, W2, b2, W3, b3, outp);
}

// Round 8
// 164.287 us; speedup vs baseline: 18.5110x; 1.1890x over previous
//
#include <hip/hip_runtime.h>
#include <hip/hip_bf16.h>

#define BB 16
#define NN 500
#define DD 128
#define QKC 256         // 2 branches * 8 heads * 16 kd

typedef unsigned short u16;
typedef unsigned int u32;
typedef __attribute__((ext_vector_type(8))) short bf16x8;   // MFMA A/B frag
typedef __attribute__((ext_vector_type(16))) float f32x16;  // MFMA C/D frag

// ---- ws layout (bytes) ----
#define GB_OFF   0          // gbias [16 b][2 br][128] f32 = 16384
#define WT_OFF   16384      // 4 mats * (hi 16384 + lo 16384) u16 = 262144
#define PT_OFF   278528     // 2 mats * (hi+lo) = 131072
#define QC_OFF   409600     // 8000*256 u16 = 4096000
#define KC_OFF   4505600    // same
#define PM_OFF   QC_OFF     // pmax [16][2][8][128] f32 = 131072, aliased into Qc
                            // (written by k_prep, read by k_gbias, THEN k_fused
                            //  overwrites the region with Qc)

__device__ inline u16 f2bf(float f) {
  __hip_bfloat16 h = __float2bfloat16(f);
  return *(u16*)&h;
}
__device__ inline float bf2f(u16 s) {
  union { u32 u; float f; } uf; uf.u = ((u32)s) << 16; return uf.f;
}

// ================= K_PREP =================
// bid 0..63:   W -> WT[c][k] split hi/lo bf16 (Wq scaled by 0.25 = NORM)
// bid 64..95:  P_node -> PT[o][k] split hi/lo
// bid 96..351: per (b,branch,chunk-of-63-rows) partial max -> pmax
__global__ __launch_bounds__(256) void k_prep(
    const float* __restrict__ h_em, const float* __restrict__ pos_em,
    const float* __restrict__ Wq_pos, const float* __restrict__ Wk_pos,
    const float* __restrict__ Wq_node, const float* __restrict__ Wk_node,
    const float* __restrict__ Pnp, const float* __restrict__ Pnn,
    float* __restrict__ pmax, u16* __restrict__ wt, u16* __restrict__ pt) {
  int bid = blockIdx.x, t = threadIdx.x;
  __shared__ float smx[2][128];
  if (bid < 64) {
    int task = bid * 256 + t;
    int m = task >> 12, rem = task & 4095;
    int c = rem >> 5, k0 = (rem & 31) * 4;
    const float* src = (m == 0) ? Wq_pos : (m == 1) ? Wk_pos : (m == 2) ? Wq_node : Wk_node;
    float scale = (m & 1) ? 1.f : 0.25f;
    int h = c >> 4, kd = c & 15;
    u16 hs[4], ls[4];
    #pragma unroll
    for (int j = 0; j < 4; ++j) {
      float v = src[h * 2048 + (k0 + j) * 16 + kd] * scale;
      hs[j] = f2bf(v);
      ls[j] = f2bf(v - bf2f(hs[j]));
    }
    u16* dst = wt + m * 32768 + c * 128 + k0;
    *(uint2*)dst = make_uint2((u32)hs[0] | ((u32)hs[1] << 16), (u32)hs[2] | ((u32)hs[3] << 16));
    *(uint2*)(dst + 16384) = make_uint2((u32)ls[0] | ((u32)ls[1] << 16), (u32)ls[2] | ((u32)ls[3] << 16));
  } else if (bid < 96) {
    int task = (bid - 64) * 256 + t;
    int m = task >> 12, rem = task & 4095;
    int o = rem >> 5, k0 = (rem & 31) * 4;
    const float* src = m ? Pnn : Pnp;
    u16 hs[4], ls[4];
    #pragma unroll
    for (int j = 0; j < 4; ++j) {
      float v = src[(k0 + j) * 128 + o];
      hs[j] = f2bf(v);
      ls[j] = f2bf(v - bf2f(hs[j]));
    }
    u16* dst = pt + m * 32768 + o * 128 + k0;
    *(uint2*)dst = make_uint2((u32)hs[0] | ((u32)hs[1] << 16), (u32)hs[2] | ((u32)hs[3] << 16));
    *(uint2*)(dst + 16384) = make_uint2((u32)ls[0] | ((u32)ls[1] << 16), (u32)ls[2] | ((u32)ls[3] << 16));
  } else {
    int id = bid - 96;              // 0..255
    int b = id >> 4, br = (id >> 3) & 1, ch = id & 7;
    const float* em = br ? h_em : pos_em;
    int n0 = ch * 63, n1 = min(NN, n0 + 63);
    int d = t & 127, s = t >> 7;
    float v = -1e30f;
    for (int n = n0 + s; n < n1; n += 2)
      v = fmaxf(v, em[((size_t)b * NN + n) * DD + d]);
    smx[s][d] = v;
    __syncthreads();
    if (t < 128)
      pmax[(((b * 2 + br) * 8) + ch) * 128 + t] = fmaxf(smx[0][t], smx[1][t]);
  }
}

// ================= K_GBIAS =================
// 32 blocks (b,br) x 128 threads: reduce 8 partial maxes, project -> gbias
__global__ __launch_bounds__(128) void k_gbias(
    const float* __restrict__ pmax,
    const float* __restrict__ Pgp, const float* __restrict__ Pgn,
    float* __restrict__ gbias) {
  int b = blockIdx.x, br = blockIdx.y, t = threadIdx.x;
  const float* Pg = br ? Pgn : Pgp;
  __shared__ float smx[128];
  const float* base = pmax + (size_t)(b * 2 + br) * 8 * 128;
  float v = base[t];
  #pragma unroll
  for (int ch = 1; ch < 8; ++ch) v = fmaxf(v, base[ch * 128 + t]);
  smx[t] = v;
  __syncthreads();
  float a = 0.f;
  #pragma unroll 8
  for (int k = 0; k < 128; ++k) a = fmaf(smx[k], Pg[k * 128 + t], a);
  gbias[(b * 2 + br) * 128 + t] = a;
}

// ================= K_FUSED (round-7 verbatim) =================
__global__ __launch_bounds__(256) void k_fused(
    const float* __restrict__ h_em, const float* __restrict__ pos_em,
    const float* __restrict__ gbias, const u16* __restrict__ wt, const u16* __restrict__ pt,
    u16* __restrict__ Qc, u16* __restrict__ Kc) {
  __shared__ __align__(16) char sm[81920];
  u16* Ah = (u16*)sm;             // [32][128] swizzled: slot ^ (row&15)
  u16* Al = (u16*)(sm + 8192);
  u16* Bh = (u16*)(sm + 16384);   // [128][128]
  u16* Bl = (u16*)(sm + 49152);
  int t = threadIdx.x, l = t & 63, w = t >> 6, o = l & 31, q = l >> 5;
  int r0 = blockIdx.x * 32, br = blockIdx.y;
  const float* em = br ? h_em : pos_em;
  int b0 = r0 / NN;
  int bsplit = (b0 + 1) * NN - r0;
  int be = min(b0 + 1, BB - 1);
  int col = w * 32 + o;
  float gA0 = gbias[(b0 * 2 + br) * 128 + col];
  float gA1 = gbias[(be * 2 + br) * 128 + col];
  #pragma unroll
  for (int it = 0; it < 4; ++it) {
    int idx = it * 256 + t;
    int row = idx >> 5, c4 = idx & 31;
    float4 v = *(const float4*)(em + (size_t)(r0 + row) * 128 + c4 * 4);
    u16 hs[4], ls[4];
    float vv[4] = {v.x, v.y, v.z, v.w};
    #pragma unroll
    for (int j = 0; j < 4; ++j) { hs[j] = f2bf(vv[j]); ls[j] = f2bf(vv[j] - bf2f(hs[j])); }
    int off = row * 128 + (((c4 >> 1) ^ (row & 15)) << 3) + ((c4 & 1) << 2);
    *(uint2*)(Ah + off) = make_uint2((u32)hs[0] | ((u32)hs[1] << 16), (u32)hs[2] | ((u32)hs[3] << 16));
    *(uint2*)(Al + off) = make_uint2((u32)ls[0] | ((u32)ls[1] << 16), (u32)ls[2] | ((u32)ls[3] << 16));
  }
  {
    const u16* ptm = pt + br * 32768;
    #pragma unroll
    for (int it = 0; it < 8; ++it) {
      int idx = it * 256 + t;
      int c = idx >> 4, s = idx & 15;
      uint4 vh = *(const uint4*)(ptm + c * 128 + s * 8);
      uint4 vl = *(const uint4*)(ptm + 16384 + c * 128 + s * 8);
      int ss = s ^ (c & 15);
      *(uint4*)(Bh + c * 128 + ss * 8) = vh;
      *(uint4*)(Bl + c * 128 + ss * 8) = vl;
    }
  }
  __syncthreads();
  f32x16 C0;
  #pragma unroll
  for (int r = 0; r < 16; ++r) C0[r] = 0.f;
  #pragma unroll
  for (int kk = 0; kk < 8; ++kk) {
    int sl = 2 * kk + q;
    bf16x8 ah = *(const bf16x8*)(Ah + o * 128 + ((sl ^ (o & 15)) << 3));
    bf16x8 al = *(const bf16x8*)(Al + o * 128 + ((sl ^ (o & 15)) << 3));
    bf16x8 bh0 = *(const bf16x8*)(Bh + col * 128 + ((sl ^ (col & 15)) << 3));
    bf16x8 bl0 = *(const bf16x8*)(Bl + col * 128 + ((sl ^ (col & 15)) << 3));
    C0 = __builtin_amdgcn_mfma_f32_32x32x16_bf16(ah, bh0, C0, 0, 0, 0);
    C0 = __builtin_amdgcn_mfma_f32_32x32x16_bf16(al, bh0, C0, 0, 0, 0);
    C0 = __builtin_amdgcn_mfma_f32_32x32x16_bf16(ah, bl0, C0, 0, 0, 0);
  }
  __syncthreads();
  #pragma unroll
  for (int r = 0; r < 16; ++r) {
    int row = (r & 3) + 8 * (r >> 2) + 4 * q;
    float vA = C0[r] + (row >= bsplit ? gA1 : gA0);
    u16 hA = f2bf(vA);
    u16 lA = f2bf(vA - bf2f(hA));
    int oA = row * 128 + ((((col >> 3) ^ (row & 15))) << 3) + (o & 7);
    Ah[oA] = hA; Al[oA] = lA;
  }
  {
    const u16* wm = wt + (br * 2 + 0) * 32768;
    #pragma unroll
    for (int it = 0; it < 8; ++it) {
      int idx = it * 256 + t;
      int c = idx >> 4, s = idx & 15;
      uint4 vh = *(const uint4*)(wm + c * 128 + s * 8);
      uint4 vl = *(const uint4*)(wm + 16384 + c * 128 + s * 8);
      int ss = s ^ (c & 15);
      *(uint4*)(Bh + c * 128 + ss * 8) = vh;
      *(uint4*)(Bl + c * 128 + ss * 8) = vl;
    }
  }
  __syncthreads();
  #pragma unroll 1
  for (int qk = 0; qk < 2; ++qk) {
    f32x16 Q0;
    #pragma unroll
    for (int r = 0; r < 16; ++r) Q0[r] = 0.f;
    #pragma unroll
    for (int kk = 0; kk < 8; ++kk) {
      int sl = 2 * kk + q;
      bf16x8 ah = *(const bf16x8*)(Ah + o * 128 + ((sl ^ (o & 15)) << 3));
      bf16x8 al = *(const bf16x8*)(Al + o * 128 + ((sl ^ (o & 15)) << 3));
      bf16x8 bh0 = *(const bf16x8*)(Bh + col * 128 + ((sl ^ (col & 15)) << 3));
      bf16x8 bl0 = *(const bf16x8*)(Bl + col * 128 + ((sl ^ (col & 15)) << 3));
      Q0 = __builtin_amdgcn_mfma_f32_32x32x16_bf16(ah, bh0, Q0, 0, 0, 0);
      Q0 = __builtin_amdgcn_mfma_f32_32x32x16_bf16(al, bh0, Q0, 0, 0, 0);
      Q0 = __builtin_amdgcn_mfma_f32_32x32x16_bf16(ah, bl0, Q0, 0, 0, 0);
    }
    u16* dst = qk ? Kc : Qc;
    #pragma unroll
    for (int r = 0; r < 16; ++r) {
      int rl_ = (r & 3) + 8 * (r >> 2) + 4 * q;
      dst[(size_t)(r0 + rl_) * QKC + br * 128 + col] = f2bf(Q0[r]);
    }
    if (qk == 0) {
      __syncthreads();
      const u16* wm = wt + (br * 2 + 1) * 32768;
      #pragma unroll
      for (int it = 0; it < 8; ++it) {
        int idx = it * 256 + t;
        int c = idx >> 4, s = idx & 15;
        uint4 vh = *(const uint4*)(wm + c * 128 + s * 8);
        uint4 vl = *(const uint4*)(wm + 16384 + c * 128 + s * 8);
        int ss = s ^ (c & 15);
        *(uint4*)(Bh + c * 128 + ss * 8) = vh;
        *(uint4*)(Bl + c * 128 + ss * 8) = vl;
      }
      __syncthreads();
    }
  }
}

// ================= K_MAIN (round-7 verbatim) =================
__global__ __launch_bounds__(256) void k_main(
    const u16* __restrict__ Qc, const u16* __restrict__ Kc,
    const float* __restrict__ W1, const float* __restrict__ b1,
    const float* __restrict__ W2, const float* __restrict__ b2,
    const float* __restrict__ W3, const float* __restrict__ b3,
    float* __restrict__ out) {
  __shared__ __align__(16) char sm[49152];
  u16* CM = (u16*)sm;             // [32 i][32 j][24] (16 ch + 8 pad)
  int t = threadIdx.x, l = t & 63, w = t >> 6, o = l & 31, q = l >> 5;
  int b = blockIdx.z, i0 = blockIdx.y * 32, j0 = blockIdx.x * 32;

  bf16x8 w1f, w2f0, w2f1;
  #pragma unroll
  for (int e = 0; e < 8; ++e) {
    int s1 = 8 * (e >> 2) + 4 * q + (e & 3);
    w1f[e]  = (short)f2bf(W1[(8 * q + e) * 32 + o]);
    w2f0[e] = (short)f2bf(W2[s1 * 32 + o]);
    w2f1[e] = (short)f2bf(W2[(16 + s1) * 32 + o]);
  }
  f32x16 b1f, b2f;
  float vw3s[16];
  #pragma unroll
  for (int r = 0; r < 16; ++r) {
    int ch = (r & 3) + 8 * (r >> 2) + 4 * q;
    b1f[r] = b1[ch]; b2f[r] = b2[ch]; vw3s[r] = W3[ch];
  }
  float b3v = b3[0];

  int gi = i0 + o; if (gi >= NN) gi = NN - 1;
  int gj = j0 + o; if (gj >= NN) gj = NN - 1;
  const u16* qrow = Qc + ((size_t)b * NN + gi) * QKC + q * 8;
  const u16* krow = Kc + ((size_t)b * NN + gj) * QKC + q * 8;
  {
    f32x16 cz;
    #pragma unroll
    for (int r = 0; r < 16; ++r) cz[r] = 0.f;
    f32x16 cc[4];
    #pragma unroll
    for (int m = 0; m < 4; ++m) {
      int ch = 4 * w + m;
      bf16x8 a  = *(const bf16x8*)(qrow + ch * 16);
      bf16x8 bb = *(const bf16x8*)(krow + ch * 16);
      cc[m] = __builtin_amdgcn_mfma_f32_32x32x16_bf16(a, bb, cz, 0, 0, 0);
    }
    #pragma unroll
    for (int r = 0; r < 16; ++r) {
      int i = (r & 3) + 8 * (r >> 2) + 4 * q;
      u32 d0 = (u32)f2bf(cc[0][r]) | ((u32)f2bf(cc[1][r]) << 16);
      u32 d1 = (u32)f2bf(cc[2][r]) | ((u32)f2bf(cc[3][r]) << 16);
      *(uint2*)(CM + i * 768 + o * 24 + 4 * w) = make_uint2(d0, d1);
    }
  }
  __syncthreads();

  #pragma unroll 1
  for (int s = 0; s < 8; ++s) {
    int i = 8 * w + s;
    int gis = i0 + i;
    bf16x8 a1 = *(const bf16x8*)(CM + i * 768 + o * 24 + 8 * q);
    f32x16 c1 = __builtin_amdgcn_mfma_f32_32x32x16_bf16(w1f, a1, b1f, 0, 0, 0);
    union { u32 w4[4]; bf16x8 v; } ba, bbu;
    #pragma unroll
    for (int p = 0; p < 4; ++p) {
      ba.w4[p]  = (u32)f2bf(fmaxf(c1[2 * p], 0.f))     | ((u32)f2bf(fmaxf(c1[2 * p + 1], 0.f)) << 16);
      bbu.w4[p] = (u32)f2bf(fmaxf(c1[8 + 2 * p], 0.f)) | ((u32)f2bf(fmaxf(c1[8 + 2 * p + 1], 0.f)) << 16);
    }
    f32x16 c2 = __builtin_amdgcn_mfma_f32_32x32x16_bf16(w2f0, ba.v, b2f, 0, 0, 0);
    c2 = __builtin_amdgcn_mfma_f32_32x32x16_bf16(w2f1, bbu.v, c2, 0, 0, 0);
    float acc = 0.f;
    #pragma unroll
    for (int r = 0; r < 16; ++r)
      acc = fmaf(fmaxf(c2[r], 0.f), vw3s[r], acc);
    acc += __shfl_xor(acc, 32);
    if (l < 32 && gis < NN && j0 + o < NN)
      out[((size_t)b * NN + gis) * NN + j0 + o] = acc + b3v;
  }
}

extern "C" void kernel_launch(void* const* d_in, const int* in_sizes, int n_in,
                              void* d_out, int out_size, void* d_ws, size_t ws_size,
                              hipStream_t stream) {
  const float* h_em    = (const float*)d_in[0];
  const float* pos_em  = (const float*)d_in[1];
  const float* Wq_pos  = (const float*)d_in[3];
  const float* Wk_pos  = (const float*)d_in[4];
  const float* Wq_node = (const float*)d_in[5];
  const float* Wk_node = (const float*)d_in[6];
  const float* Pgp     = (const float*)d_in[7];
  const float* Pgn     = (const float*)d_in[8];
  const float* Pnp     = (const float*)d_in[9];
  const float* Pnn     = (const float*)d_in[10];
  const float* W1 = (const float*)d_in[11];
  const float* b1 = (const float*)d_in[12];
  const float* W2 = (const float*)d_in[13];
  const float* b2 = (const float*)d_in[14];
  const float* W3 = (const float*)d_in[15];
  const float* b3 = (const float*)d_in[16];
  float* outp = (float*)d_out;

  char* ws = (char*)d_ws;
  float* gbias = (float*)(ws + GB_OFF);
  u16* wt = (u16*)(ws + WT_OFF);
  u16* pt = (u16*)(ws + PT_OFF);
  u16* Qc = (u16*)(ws + QC_OFF);
  u16* Kc = (u16*)(ws + KC_OFF);
  float* pmax = (float*)(ws + PM_OFF);

  hipLaunchKernelGGL(k_prep, dim3(352), dim3(256), 0, stream,
                     h_em, pos_em, Wq_pos, Wk_pos, Wq_node, Wk_node,
                     Pnp, Pnn, pmax, wt, pt);
  hipLaunchKernelGGL(k_gbias, dim3(16, 2), dim3(128), 0, stream,
                     pmax, Pgp, Pgn, gbias);
  hipLaunchKernelGGL(k_fused, dim3(250, 2), dim3(256), 0, stream,
                     h_em, pos_em, gbias, wt, pt, Qc, Kc);
  hipLaunchKernelGGL(k_main, dim3(16, 16, BB), dim3(256), 0, stream,
                     Qc, Kc, W1, b1, W2, b2, W3, b3, outp);
}

// Round 9
// 154.540 us; speedup vs baseline: 19.6785x; 1.0631x over previous
//
#include <hip/hip_runtime.h>
#include <hip/hip_bf16.h>

#define BB 16
#define NN 500
#define DD 128
#define QKC 256         // 2 branches * 8 heads * 16 kd

typedef unsigned short u16;
typedef unsigned int u32;
typedef __attribute__((ext_vector_type(8))) short bf16x8;   // MFMA A/B frag
typedef __attribute__((ext_vector_type(16))) float f32x16;  // MFMA C/D frag

// ---- ws layout (bytes) ----
#define GB_OFF   0          // gbias [16 b][2 br][128] f32 = 16384
#define WT_OFF   16384      // 4 mats * (hi 16384 + lo 16384) u16 = 262144
#define PT_OFF   278528     // 2 mats * (hi+lo) = 131072
#define QC_OFF   409600     // 8000*256 u16 = 4096000
#define KC_OFF   4505600    // same
#define PM_OFF   QC_OFF     // pmax [16][2][8][128] f32, aliased into Qc region

// hardware bf16 convert: D.lo = bf16(lo), D.hi = bf16(hi)  [1 VALU inst]
__device__ inline u32 pk2(float lo, float hi) {
  u32 r;
  asm("v_cvt_pk_bf16_f32 %0, %1, %2" : "=v"(r) : "v"(lo), "v"(hi));
  return r;
}
__device__ inline u16 f2bf(float f) {
  u32 r;
  asm("v_cvt_pk_bf16_f32 %0, %1, %1" : "=v"(r) : "v"(f));
  return (u16)r;
}
__device__ inline float bf2f(u16 s) {
  union { u32 u; float f; } uf; uf.u = ((u32)s) << 16; return uf.f;
}

// ================= K_PREP =================
// bid 0..63:   W -> WT[c][k] split hi/lo bf16 (Wq scaled by 0.25 = NORM)
// bid 64..95:  P_node -> PT[o][k] split hi/lo
// bid 96..351: per (b,branch,chunk-of-63-rows) partial max -> pmax
__global__ __launch_bounds__(256) void k_prep(
    const float* __restrict__ h_em, const float* __restrict__ pos_em,
    const float* __restrict__ Wq_pos, const float* __restrict__ Wk_pos,
    const float* __restrict__ Wq_node, const float* __restrict__ Wk_node,
    const float* __restrict__ Pnp, const float* __restrict__ Pnn,
    float* __restrict__ pmax, u16* __restrict__ wt, u16* __restrict__ pt) {
  int bid = blockIdx.x, t = threadIdx.x;
  __shared__ float smx[2][128];
  if (bid < 64) {
    int task = bid * 256 + t;
    int m = task >> 12, rem = task & 4095;
    int c = rem >> 5, k0 = (rem & 31) * 4;
    const float* src = (m == 0) ? Wq_pos : (m == 1) ? Wk_pos : (m == 2) ? Wq_node : Wk_node;
    float scale = (m & 1) ? 1.f : 0.25f;
    int h = c >> 4, kd = c & 15;
    float v[4];
    #pragma unroll
    for (int j = 0; j < 4; ++j) v[j] = src[h * 2048 + (k0 + j) * 16 + kd] * scale;
    u32 h01 = pk2(v[0], v[1]), h23 = pk2(v[2], v[3]);
    u32 l01 = pk2(v[0] - bf2f((u16)h01), v[1] - bf2f((u16)(h01 >> 16)));
    u32 l23 = pk2(v[2] - bf2f((u16)h23), v[3] - bf2f((u16)(h23 >> 16)));
    u16* dst = wt + m * 32768 + c * 128 + k0;
    *(uint2*)dst = make_uint2(h01, h23);
    *(uint2*)(dst + 16384) = make_uint2(l01, l23);
  } else if (bid < 96) {
    int task = (bid - 64) * 256 + t;
    int m = task >> 12, rem = task & 4095;
    int o = rem >> 5, k0 = (rem & 31) * 4;
    const float* src = m ? Pnn : Pnp;
    float v[4];
    #pragma unroll
    for (int j = 0; j < 4; ++j) v[j] = src[(k0 + j) * 128 + o];
    u32 h01 = pk2(v[0], v[1]), h23 = pk2(v[2], v[3]);
    u32 l01 = pk2(v[0] - bf2f((u16)h01), v[1] - bf2f((u16)(h01 >> 16)));
    u32 l23 = pk2(v[2] - bf2f((u16)h23), v[3] - bf2f((u16)(h23 >> 16)));
    u16* dst = pt + m * 32768 + o * 128 + k0;
    *(uint2*)dst = make_uint2(h01, h23);
    *(uint2*)(dst + 16384) = make_uint2(l01, l23);
  } else {
    int id = bid - 96;              // 0..255
    int b = id >> 4, br = (id >> 3) & 1, ch = id & 7;
    const float* em = br ? h_em : pos_em;
    int n0 = ch * 63, n1 = min(NN, n0 + 63);
    int d = t & 127, s = t >> 7;
    float v = -1e30f;
    for (int n = n0 + s; n < n1; n += 2)
      v = fmaxf(v, em[((size_t)b * NN + n) * DD + d]);
    smx[s][d] = v;
    __syncthreads();
    if (t < 128)
      pmax[(((b * 2 + br) * 8) + ch) * 128 + t] = fmaxf(smx[0][t], smx[1][t]);
  }
}

// ================= K_GBIAS =================
__global__ __launch_bounds__(128) void k_gbias(
    const float* __restrict__ pmax,
    const float* __restrict__ Pgp, const float* __restrict__ Pgn,
    float* __restrict__ gbias) {
  int b = blockIdx.x, br = blockIdx.y, t = threadIdx.x;
  const float* Pg = br ? Pgn : Pgp;
  __shared__ float smx[128];
  const float* base = pmax + (size_t)(b * 2 + br) * 8 * 128;
  float v = base[t];
  #pragma unroll
  for (int ch = 1; ch < 8; ++ch) v = fmaxf(v, base[ch * 128 + t]);
  smx[t] = v;
  __syncthreads();
  float a = 0.f;
  #pragma unroll 8
  for (int k = 0; k < 128; ++k) a = fmaf(smx[k], Pg[k * 128 + t], a);
  gbias[(b * 2 + br) * 128 + t] = a;
}

// ================= K_FUSED =================
// Per block: 32 rows x 1 branch. refine GEMM (split bf16) + gbias
// -> H in LDS (split) -> Q GEMM -> K GEMM. LDS 80 KB -> 2 blocks/CU.
__global__ __launch_bounds__(256) void k_fused(
    const float* __restrict__ h_em, const float* __restrict__ pos_em,
    const float* __restrict__ gbias, const u16* __restrict__ wt, const u16* __restrict__ pt,
    u16* __restrict__ Qc, u16* __restrict__ Kc) {
  __shared__ __align__(16) char sm[81920];
  u16* Ah = (u16*)sm;             // [32][128] swizzled: slot ^ (row&15)
  u16* Al = (u16*)(sm + 8192);
  u16* Bh = (u16*)(sm + 16384);   // [128][128]
  u16* Bl = (u16*)(sm + 49152);
  int t = threadIdx.x, l = t & 63, w = t >> 6, o = l & 31, q = l >> 5;
  int r0 = blockIdx.x * 32, br = blockIdx.y;
  const float* em = br ? h_em : pos_em;
  int b0 = r0 / NN;
  int bsplit = (b0 + 1) * NN - r0;
  int be = min(b0 + 1, BB - 1);
  int col = w * 32 + o;
  float gA0 = gbias[(b0 * 2 + br) * 128 + col];
  float gA1 = gbias[(be * 2 + br) * 128 + col];
  #pragma unroll
  for (int it = 0; it < 4; ++it) {
    int idx = it * 256 + t;
    int row = idx >> 5, c4 = idx & 31;
    float4 v = *(const float4*)(em + (size_t)(r0 + row) * 128 + c4 * 4);
    u32 h01 = pk2(v.x, v.y), h23 = pk2(v.z, v.w);
    u32 l01 = pk2(v.x - bf2f((u16)h01), v.y - bf2f((u16)(h01 >> 16)));
    u32 l23 = pk2(v.z - bf2f((u16)h23), v.w - bf2f((u16)(h23 >> 16)));
    int off = row * 128 + (((c4 >> 1) ^ (row & 15)) << 3) + ((c4 & 1) << 2);
    *(uint2*)(Ah + off) = make_uint2(h01, h23);
    *(uint2*)(Al + off) = make_uint2(l01, l23);
  }
  {
    const u16* ptm = pt + br * 32768;
    #pragma unroll
    for (int it = 0; it < 8; ++it) {
      int idx = it * 256 + t;
      int c = idx >> 4, s = idx & 15;
      uint4 vh = *(const uint4*)(ptm + c * 128 + s * 8);
      uint4 vl = *(const uint4*)(ptm + 16384 + c * 128 + s * 8);
      int ss = s ^ (c & 15);
      *(uint4*)(Bh + c * 128 + ss * 8) = vh;
      *(uint4*)(Bl + c * 128 + ss * 8) = vl;
    }
  }
  __syncthreads();
  f32x16 C0;
  #pragma unroll
  for (int r = 0; r < 16; ++r) C0[r] = 0.f;
  #pragma unroll
  for (int kk = 0; kk < 8; ++kk) {
    int sl = 2 * kk + q;
    bf16x8 ah = *(const bf16x8*)(Ah + o * 128 + ((sl ^ (o & 15)) << 3));
    bf16x8 al = *(const bf16x8*)(Al + o * 128 + ((sl ^ (o & 15)) << 3));
    bf16x8 bh0 = *(const bf16x8*)(Bh + col * 128 + ((sl ^ (col & 15)) << 3));
    bf16x8 bl0 = *(const bf16x8*)(Bl + col * 128 + ((sl ^ (col & 15)) << 3));
    C0 = __builtin_amdgcn_mfma_f32_32x32x16_bf16(ah, bh0, C0, 0, 0, 0);
    C0 = __builtin_amdgcn_mfma_f32_32x32x16_bf16(al, bh0, C0, 0, 0, 0);
    C0 = __builtin_amdgcn_mfma_f32_32x32x16_bf16(ah, bl0, C0, 0, 0, 0);
  }
  __syncthreads();
  #pragma unroll
  for (int r = 0; r < 16; ++r) {
    int row = (r & 3) + 8 * (r >> 2) + 4 * q;
    float vA = C0[r] + (row >= bsplit ? gA1 : gA0);
    u16 hA = f2bf(vA);
    u16 lA = f2bf(vA - bf2f(hA));
    int oA = row * 128 + ((((col >> 3) ^ (row & 15))) << 3) + (o & 7);
    Ah[oA] = hA; Al[oA] = lA;
  }
  {
    const u16* wm = wt + (br * 2 + 0) * 32768;
    #pragma unroll
    for (int it = 0; it < 8; ++it) {
      int idx = it * 256 + t;
      int c = idx >> 4, s = idx & 15;
      uint4 vh = *(const uint4*)(wm + c * 128 + s * 8);
      uint4 vl = *(const uint4*)(wm + 16384 + c * 128 + s * 8);
      int ss = s ^ (c & 15);
      *(uint4*)(Bh + c * 128 + ss * 8) = vh;
      *(uint4*)(Bl + c * 128 + ss * 8) = vl;
    }
  }
  __syncthreads();
  #pragma unroll 1
  for (int qk = 0; qk < 2; ++qk) {
    f32x16 Q0;
    #pragma unroll
    for (int r = 0; r < 16; ++r) Q0[r] = 0.f;
    #pragma unroll
    for (int kk = 0; kk < 8; ++kk) {
      int sl = 2 * kk + q;
      bf16x8 ah = *(const bf16x8*)(Ah + o * 128 + ((sl ^ (o & 15)) << 3));
      bf16x8 al = *(const bf16x8*)(Al + o * 128 + ((sl ^ (o & 15)) << 3));
      bf16x8 bh0 = *(const bf16x8*)(Bh + col * 128 + ((sl ^ (col & 15)) << 3));
      bf16x8 bl0 = *(const bf16x8*)(Bl + col * 128 + ((sl ^ (col & 15)) << 3));
      Q0 = __builtin_amdgcn_mfma_f32_32x32x16_bf16(ah, bh0, Q0, 0, 0, 0);
      Q0 = __builtin_amdgcn_mfma_f32_32x32x16_bf16(al, bh0, Q0, 0, 0, 0);
      Q0 = __builtin_amdgcn_mfma_f32_32x32x16_bf16(ah, bl0, Q0, 0, 0, 0);
    }
    u16* dst = qk ? Kc : Qc;
    #pragma unroll
    for (int r = 0; r < 16; ++r) {
      int rl_ = (r & 3) + 8 * (r >> 2) + 4 * q;
      dst[(size_t)(r0 + rl_) * QKC + br * 128 + col] = f2bf(Q0[r]);
    }
    if (qk == 0) {
      __syncthreads();
      const u16* wm = wt + (br * 2 + 1) * 32768;
      #pragma unroll
      for (int it = 0; it < 8; ++it) {
        int idx = it * 256 + t;
        int c = idx >> 4, s = idx & 15;
        uint4 vh = *(const uint4*)(wm + c * 128 + s * 8);
        uint4 vl = *(const uint4*)(wm + 16384 + c * 128 + s * 8);
        int ss = s ^ (c & 15);
        *(uint4*)(Bh + c * 128 + ss * 8) = vh;
        *(uint4*)(Bl + c * 128 + ss * 8) = vl;
      }
      __syncthreads();
    }
  }
}

// ================= K_MAIN =================
// 32x32 pair tile. Compat frags direct from global; CM stride 20 u16 (40 B
// rows: 10-dword stride, 2-way bank = free; b64-aligned). MLP in registers,
// sigma-permuted W2 (zero shuffles). LDS 40 KB -> 4 blocks/CU.
__global__ __launch_bounds__(256) void k_main(
    const u16* __restrict__ Qc, const u16* __restrict__ Kc,
    const float* __restrict__ W1, const float* __restrict__ b1,
    const float* __restrict__ W2, const float* __restrict__ b2,
    const float* __restrict__ W3, const float* __restrict__ b3,
    float* __restrict__ out) {
  __shared__ __align__(16) char sm[40960];
  u16* CM = (u16*)sm;             // [32 i][32 j][20] (16 ch + 4 pad)
  int t = threadIdx.x, l = t & 63, w = t >> 6, o = l & 31, q = l >> 5;
  int b = blockIdx.z, i0 = blockIdx.y * 32, j0 = blockIdx.x * 32;

  bf16x8 w1f, w2f0, w2f1;
  #pragma unroll
  for (int e = 0; e < 8; ++e) {
    int s1 = 8 * (e >> 2) + 4 * q + (e & 3);
    w1f[e]  = (short)f2bf(W1[(8 * q + e) * 32 + o]);
    w2f0[e] = (short)f2bf(W2[s1 * 32 + o]);
    w2f1[e] = (short)f2bf(W2[(16 + s1) * 32 + o]);
  }
  f32x16 b1f, b2f;
  float vw3s[16];
  #pragma unroll
  for (int r = 0; r < 16; ++r) {
    int ch = (r & 3) + 8 * (r >> 2) + 4 * q;
    b1f[r] = b1[ch]; b2f[r] = b2[ch]; vw3s[r] = W3[ch];
  }
  float b3v = b3[0];

  int gi = i0 + o; if (gi >= NN) gi = NN - 1;
  int gj = j0 + o; if (gj >= NN) gj = NN - 1;
  const u16* qrow = Qc + ((size_t)b * NN + gi) * QKC + q * 8;
  const u16* krow = Kc + ((size_t)b * NN + gj) * QKC + q * 8;
  {
    f32x16 cz;
    #pragma unroll
    for (int r = 0; r < 16; ++r) cz[r] = 0.f;
    f32x16 cc[4];
    #pragma unroll
    for (int m = 0; m < 4; ++m) {
      int ch = 4 * w + m;
      bf16x8 a  = *(const bf16x8*)(qrow + ch * 16);
      bf16x8 bb = *(const bf16x8*)(krow + ch * 16);
      cc[m] = __builtin_amdgcn_mfma_f32_32x32x16_bf16(a, bb, cz, 0, 0, 0);
    }
    #pragma unroll
    for (int r = 0; r < 16; ++r) {
      int i = (r & 3) + 8 * (r >> 2) + 4 * q;
      u32 d0 = pk2(cc[0][r], cc[1][r]);
      u32 d1 = pk2(cc[2][r], cc[3][r]);
      *(uint2*)(CM + i * 640 + o * 20 + 4 * w) = make_uint2(d0, d1);
    }
  }
  __syncthreads();

  #pragma unroll 1
  for (int s = 0; s < 8; ++s) {
    int i = 8 * w + s;
    int gis = i0 + i;
    const u16* cp = CM + i * 640 + o * 20 + 8 * q;
    uint2 a1lo = *(const uint2*)cp;
    uint2 a1hi = *(const uint2*)(cp + 4);
    union { u32 w4[4]; bf16x8 v; } a1u;
    a1u.w4[0] = a1lo.x; a1u.w4[1] = a1lo.y; a1u.w4[2] = a1hi.x; a1u.w4[3] = a1hi.y;
    f32x16 c1 = __builtin_amdgcn_mfma_f32_32x32x16_bf16(w1f, a1u.v, b1f, 0, 0, 0);
    union { u32 w4[4]; bf16x8 v; } ba, bbu;
    #pragma unroll
    for (int p = 0; p < 4; ++p) {
      ba.w4[p]  = pk2(fmaxf(c1[2 * p], 0.f),     fmaxf(c1[2 * p + 1], 0.f));
      bbu.w4[p] = pk2(fmaxf(c1[8 + 2 * p], 0.f), fmaxf(c1[8 + 2 * p + 1], 0.f));
    }
    f32x16 c2 = __builtin_amdgcn_mfma_f32_32x32x16_bf16(w2f0, ba.v, b2f, 0, 0, 0);
    c2 = __builtin_amdgcn_mfma_f32_32x32x16_bf16(w2f1, bbu.v, c2, 0, 0, 0);
    float acc = 0.f;
    #pragma unroll
    for (int r = 0; r < 16; ++r)
      acc = fmaf(fmaxf(c2[r], 0.f), vw3s[r], acc);
    acc += __shfl_xor(acc, 32);
    if (l < 32 && gis < NN && j0 + o < NN)
      out[((size_t)b * NN + gis) * NN + j0 + o] = acc + b3v;
  }
}

extern "C" void kernel_launch(void* const* d_in, const int* in_sizes, int n_in,
                              void* d_out, int out_size, void* d_ws, size_t ws_size,
                              hipStream_t stream) {
  const float* h_em    = (const float*)d_in[0];
  const float* pos_em  = (const float*)d_in[1];
  const float* Wq_pos  = (const float*)d_in[3];
  const float* Wk_pos  = (const float*)d_in[4];
  const float* Wq_node = (const float*)d_in[5];
  const float* Wk_node = (const float*)d_in[6];
  const float* Pgp     = (const float*)d_in[7];
  const float* Pgn     = (const float*)d_in[8];
  const float* Pnp     = (const float*)d_in[9];
  const float* Pnn     = (const float*)d_in[10];
  const float* W1 = (const float*)d_in[11];
  const float* b1 = (const float*)d_in[12];
  const float* W2 = (const float*)d_in[13];
  const float* b2 = (const float*)d_in[14];
  const float* W3 = (const float*)d_in[15];
  const float* b3 = (const float*)d_in[16];
  float* outp = (float*)d_out;

  char* ws = (char*)d_ws;
  float* gbias = (float*)(ws + GB_OFF);
  u16* wt = (u16*)(ws + WT_OFF);
  u16* pt = (u16*)(ws + PT_OFF);
  u16* Qc = (u16*)(ws + QC_OFF);
  u16* Kc = (u16*)(ws + KC_OFF);
  float* pmax = (float*)(ws + PM_OFF);

  hipLaunchKernelGGL(k_prep, dim3(352), dim3(256), 0, stream,
                     h_em, pos_em, Wq_pos, Wk_pos, Wq_node, Wk_node,
                     Pnp, Pnn, pmax, wt, pt);
  hipLaunchKernelGGL(k_gbias, dim3(16, 2), dim3(128), 0, stream,
                     pmax, Pgp, Pgn, gbias);
  hipLaunchKernelGGL(k_fused, dim3(250, 2), dim3(256), 0, stream,
                     h_em, pos_em, gbias, wt, pt, Qc, Kc);
  hipLaunchKernelGGL(k_main, dim3(16, 16, BB), dim3(256), 0, stream,
                     Qc, Kc, W1, b1, W2, b2, W3, b3, outp);
}